// Round 12
// baseline (780.102 us; speedup 1.0000x reference)
//
#include <hip/hip_runtime.h>
#include <stdint.h>

typedef unsigned short u16;
typedef __attribute__((ext_vector_type(8))) short bh8;   // 8 x bf16 (bits)
typedef __attribute__((ext_vector_type(4))) float f4;

__device__ __forceinline__ float b2f(u16 u){ union{unsigned u; float f;} x; x.u = ((unsigned)u)<<16; return x.f; }
__device__ __forceinline__ u16 f2b(float f){ union{float f; unsigned u;} x; x.f = f; return (u16)((x.u + 0x7fffu + ((x.u>>16)&1u))>>16); }
__device__ __forceinline__ bh8 ld8(const u16* p){ return *reinterpret_cast<const bh8*>(p); }

// bijective XCD-chunked block swizzle (m204 form)
__device__ __forceinline__ int xcd_swz(int bid, int nwg){
  int q = nwg >> 3, r = nwg & 7;
  int x = bid & 7, k = bid >> 3;
  return (x < r ? x*(q+1) : r*(q+1) + (x - r)*q) + k;
}

// ---------------- graph preprocessing: bucketed counting-sort CSR build ----------------
#define NBK 512   // bucket slots (real buckets = ceil(N/128) <= 391)

__global__ __launch_bounds__(256) void k_hist(const int* dst, int* hist, int E){
  __shared__ int h[NBK];
  for (int i=threadIdx.x;i<NBK;i+=256) h[i]=0;
  __syncthreads();
  int stride = 256*gridDim.x;
  for (int i = blockIdx.x*256+threadIdx.x; i<E; i+=stride)
    atomicAdd(&h[dst[i]>>7], 1);
  __syncthreads();
  for (int i=threadIdx.x;i<NBK;i+=256){
    int v=h[i]; if (v) atomicAdd(&hist[i], v);
  }
}

__global__ __launch_bounds__(512) void k_scanb(const int* hist, int* bbase, int* bcursor){
  int t = threadIdx.x, lane = t&63, wv = t>>6;
  __shared__ int ws[8];
  int v = hist[t];
  int x = v;
  #pragma unroll
  for (int o=1;o<64;o<<=1){ int u=__shfl_up(x,(unsigned)o,64); if(lane>=o) x+=u; }
  if (lane==63) ws[wv]=x;
  __syncthreads();
  if (t<8){
    int s=ws[t];
    #pragma unroll
    for (int o=1;o<8;o<<=1){ int u=__shfl_up(s,(unsigned)o,8); if (t>=o) s+=u; }
    ws[t]=s;
  }
  __syncthreads();
  int base = (wv==0)?0:ws[wv-1];
  int ex = base + x - v;
  bbase[t]=ex; bcursor[t]=ex;
  if (t==511) bbase[512]=ex+v;
}

__global__ __launch_bounds__(256) void k_bucket(const int* src, const int* dst,
                                                int* bcursor, unsigned* bkt, int E, int nblk){
  __shared__ int h[NBK], base[NBK], lc[NBK];
  int per = (E + nblk - 1)/nblk;
  int e0 = blockIdx.x*per, e1 = min(E, e0+per);
  for (int i=threadIdx.x;i<NBK;i+=256){ h[i]=0; lc[i]=0; }
  __syncthreads();
  for (int e=e0+threadIdx.x; e<e1; e+=256) atomicAdd(&h[dst[e]>>7], 1);
  __syncthreads();
  for (int i=threadIdx.x;i<NBK;i+=256){
    int c=h[i]; base[i] = c ? atomicAdd(&bcursor[i], c) : 0;
  }
  __syncthreads();
  for (int e=e0+threadIdx.x; e<e1; e+=256){
    int d = dst[e];
    int b = d>>7;
    int r = atomicAdd(&lc[b], 1);
    bkt[base[b]+r] = ((unsigned)(d&127)<<25) | (unsigned)src[e];
  }
}

__global__ __launch_bounds__(128) void k_degb(const unsigned* bkt, const int* bbase,
                                              int* off, float* inv_deg, float* invs,
                                              int N, int E){
  int b = blockIdx.x, t = threadIdx.x;
  __shared__ int cnt[128];
  __shared__ int w0tot;
  cnt[t]=0;
  __syncthreads();
  int e0=bbase[b], e1=bbase[b+1];
  for (int e=e0+t; e<e1; e+=128) atomicAdd(&cnt[bkt[e]>>25], 1);
  __syncthreads();
  int v = cnt[t];
  int lane=t&63, wv=t>>6;
  int x=v;
  #pragma unroll
  for (int o=1;o<64;o<<=1){ int u=__shfl_up(x,(unsigned)o,64); if(lane>=o) x+=u; }
  if (t==63) w0tot=x;
  __syncthreads();
  int ex = x - v + (wv ? w0tot : 0);
  int node = b*128 + t;
  if (node < N){
    off[node] = e0 + ex;
    int d = (v<1)?1:v;
    float df=(float)d;
    inv_deg[node]=1.0f/df;
    invs[node]=rsqrtf(df);
  }
  if (b==0 && t==0) off[N]=E;
}

__global__ __launch_bounds__(128) void k_fillb(const unsigned* bkt, const int* bbase,
                                               const int* off, const float* invs,
                                               int2* csr, int N){
  int b = blockIdx.x, t = threadIdx.x;
  __shared__ int cur[128];
  int node = b*128 + t;
  cur[t] = (node < N) ? off[node] : 0;
  __syncthreads();
  int e0=bbase[b], e1=bbase[b+1];
  for (int e=e0+t; e<e1; e+=128){
    unsigned v = bkt[e];
    int i = (int)(v>>25);
    int s = (int)(v & 0x1FFFFFFu);
    int pos = atomicAdd(&cur[i], 1);
    csr[pos] = make_int2(s, __float_as_int(invs[s]));
  }
}

__global__ void k_softmax(const float* alphas, float* wmix){
  int t = threadIdx.x; int r = t >> 3, o = t & 7;
  if (r < 14){
    float v = alphas[r*8+o];
    float m = v;
    #pragma unroll
    for (int d=1; d<8; d<<=1) m = fmaxf(m, __shfl_xor(m, d, 8));
    float e = expf(v - m);
    float s = e;
    #pragma unroll
    for (int d=1; d<8; d<<=1) s += __shfl_xor(s, d, 8);
    wmix[r*8+o] = e / s;
  }
}

// ---------------- conversion / packing ----------------
__global__ void k_f2b(const float* a, u16* b, int n){
  int i = blockIdx.x*256 + threadIdx.x;
  if (i < n) b[i] = f2b(a[i]);
}

// all 7 weight-pack jobs in one launch (segmented index space).
struct PackAllArgs {
  const float* src[7];
  u16* dst[7];
  int K[7], ncol[7];
  int base[8];
};
__global__ __launch_bounds__(256) void k_packall(PackAllArgs P){
  int i = blockIdx.x*256 + threadIdx.x;
  if (i >= P.base[7]) return;
  int s = 0;
  #pragma unroll
  for (int k=1;k<7;k++) if (i >= P.base[k]) s = k;
  int e = i - P.base[s];
  if (s < 6){
    int K = P.K[s], ncol = P.ncol[s];
    int k = e / ncol, n = e - k*ncol;
    P.dst[s][(size_t)n*K + k] = f2b(P.src[s][e]);
  } else {
    int n = e >> 8, k = e & 255;
    float v = 0.f;
    if (n < 40) v = P.src[6][(size_t)(1+k)*40 + n] + P.src[6][n] * (1.f/256.f);
    P.dst[6][(size_t)n*256 + k] = f2b(v);
  }
}

// op weights with softmax-mix folding; 8 matrices per slot.
// ROUND-12: mats PERMUTED into two contiguous 32KB halves by consumer:
//   half0 (positions 0-3) = old {1,4,5,3}  (fh/fs consumers)
//   half1 (positions 4-7) = old {0,6,7,2}  (fn/fx/mean consumers)
// so k_step can ping-pong stage/compute at half granularity.
// dst layout [n][k] with the k_step XOR-swizzle baked in.
struct PackArgs { const float* W[8]; const float* wmix; u16* dst; };
__global__ void k_pack_ops8(PackArgs P){
  int i = blockIdx.x*256 + threadIdx.x;
  if (i >= 28*8*4096) return;
  int slot28 = i >> 15;
  int rem = i & 32767;
  int mat = rem >> 12;
  int e = rem & 4095;
  int k = e >> 6, n = e & 63;
  const float* wm = P.wmix + (slot28 % 14)*8;
  size_t off = (size_t)slot28*4096 + e;   // source [28][64][64] row-major [k][n]
  float v = 0.f;
  switch(mat){
    case 0: v = wm[2]*P.W[0][off]; break;
    case 1: v = wm[3]*P.W[1][off] + wm[5]*P.W[4][off] + ((k==n) ? wm[1] : 0.f); break;
    case 2: v = wm[3]*P.W[2][off]; break;
    case 3: v = wm[4]*P.W[3][off]; break;
    case 4: v = wm[5]*P.W[5][off]; break;
    case 5: v = wm[6]*P.W[6][off]; break;
    case 6: v = 0.9f*wm[7]*P.W[7][off]; break;
    case 7: v = 0.1f*wm[7]*P.W[7][off]; break;
  }
  const int perm[8] = {4,0,7,3,1,2,5,6};   // old mat id -> packed position
  P.dst[(((size_t)slot28*8 + perm[mat])<<12) + (n<<6) + (((k>>3) ^ (n&7))<<3) + (k&7)] = f2b(v);
}

// ---------------- MLP: GEMM + per-block partial stats (no global atomics) ----------------
template<int NT, int NKB>
__global__ __launch_bounds__(256) void k_gemm(const u16* A, const u16* Bp,
                                              u16* Tb, int Nn, float* Sp){
  const int K = NKB*32;
  const int ldT = NT*16;
  __shared__ float sred[4][NT*16][2];
  int tid = threadIdx.x, wv = tid>>6, lane = tid&63, q = lane>>4, t = lane&15;
  int row0 = blockIdx.x*128 + wv*32;
  f4 acc[2][NT];
  #pragma unroll
  for (int a=0;a<2;a++)
    #pragma unroll
    for (int b=0;b<NT;b++) acc[a][b] = (f4){0.f,0.f,0.f,0.f};
  const u16* arow0 = A + (size_t)(row0 + t)*K + q*8;
  const u16* arow1 = arow0 + (size_t)16*K;
  const u16* brow  = Bp + (size_t)t*K + q*8;
  #pragma unroll
  for (int kb = 0; kb < NKB; ++kb){
    bh8 a0 = ld8(arow0 + kb*32);
    bh8 a1 = ld8(arow1 + kb*32);
    #pragma unroll
    for (int nt=0; nt<NT; ++nt){
      bh8 bf = ld8(brow + (size_t)nt*16*K + kb*32);
      acc[0][nt] = __builtin_amdgcn_mfma_f32_16x16x32_bf16(a0, bf, acc[0][nt], 0, 0, 0);
      acc[1][nt] = __builtin_amdgcn_mfma_f32_16x16x32_bf16(a1, bf, acc[1][nt], 0, 0, 0);
    }
  }
  #pragma unroll
  for (int nt=0;nt<NT;nt++){
    float ps = 0.f, pq = 0.f;
    #pragma unroll
    for (int rt=0;rt<2;rt++)
      #pragma unroll
      for (int r=0;r<4;r++){
        int row = row0 + rt*16 + q*4 + r;
        float v = acc[rt][nt][r];
        if (row < Nn){
          Tb[(size_t)row*ldT + nt*16 + t] = f2b(v);
          ps += v; pq += v*v;
        }
      }
    ps += __shfl_xor(ps, 16, 64); pq += __shfl_xor(pq, 16, 64);
    ps += __shfl_xor(ps, 32, 64); pq += __shfl_xor(pq, 32, 64);
    if (q == 0){ sred[wv][nt*16 + t][0] = ps; sred[wv][nt*16 + t][1] = pq; }
  }
  __syncthreads();
  if (tid < NT*16){
    float s = sred[0][tid][0] + sred[1][tid][0] + sred[2][tid][0] + sred[3][tid][0];
    float qq = sred[0][tid][1] + sred[1][tid][1] + sred[2][tid][1] + sred[3][tid][1];
    float* sp = Sp + (size_t)blockIdx.x*(2*NT*16);
    sp[tid] = s;
    sp[NT*16 + tid] = qq;        // coalesced plain stores, no contention
  }
}

// reduce per-block partials -> S[c] (sum), S[256+c] (sumsq).
__global__ __launch_bounds__(256) void k_redstats(const float* Sp, float* S, int ncol, int nb){
  int c2 = blockIdx.x*4 + (threadIdx.x>>6);
  int lane = threadIdx.x & 63;
  if (c2 >= 2*ncol) return;
  int stride = 2*ncol;
  float s = 0.f;
  for (int b = lane; b < nb; b += 64) s += Sp[(size_t)b*stride + c2];
  #pragma unroll
  for (int m=1; m<64; m<<=1) s += __shfl_xor(s, m, 64);
  if (lane == 0){
    int c = (c2 < ncol) ? c2 : (256 + (c2 - ncol));
    S[c] = s;
  }
}

__global__ void k_norm(const u16* Tb, int ldT, int ncols, int Nn, const float* S,
                       u16* out, int rs_out, int relu, float invN){
  int i = blockIdx.x*256 + threadIdx.x;
  int nv = ncols >> 3;
  if (i >= Nn*nv) return;
  int r = i / nv, c8 = (i - r*nv)*8;
  bh8 tv = ld8(Tb + (size_t)r*ldT + c8);
  bh8 ov;
  #pragma unroll
  for (int u=0; u<8; ++u){
    int c = c8 + u;
    float m = S[c]*invN;
    float var = S[256+c]*invN - m*m;
    float xv = (b2f((u16)tv[u]) - m) * rsqrtf(var + 1e-5f);
    if (relu) xv = fmaxf(xv, 0.f);
    ov[u] = (short)f2b(xv);
  }
  *reinterpret_cast<bh8*>(out + (size_t)r*rs_out + c8) = ov;
}

// split-output norm for the fused stem+pre GEMM (256 cols in T):
// cols 0-191 -> stem_o (no relu, stride 192); cols 192-255 -> x0b (relu, stride 64)
__global__ void k_norm2(const u16* Tb, int Nn, const float* S,
                        u16* o1, u16* o2, float invN){
  int i = blockIdx.x*256 + threadIdx.x;
  if (i >= Nn*32) return;
  int r = i >> 5, c8 = (i & 31) << 3;
  bh8 tv = ld8(Tb + (size_t)r*256 + c8);
  bh8 ov;
  int relu = (c8 >= 192);
  #pragma unroll
  for (int u=0; u<8; ++u){
    int c = c8 + u;
    float m = S[c]*invN;
    float var = S[256+c]*invN - m*m;
    float xv = (b2f((u16)tv[u]) - m) * rsqrtf(var + 1e-5f);
    if (relu) xv = fmaxf(xv, 0.f);
    ov[u] = (short)f2b(xv);
  }
  if (c8 < 192)
    *reinterpret_cast<bh8*>(o1 + (size_t)r*192 + c8) = ov;
  else
    *reinterpret_cast<bh8*>(o2 + (size_t)r*64 + (c8 - 192)) = ov;
}

// ---------------- aggregation: 16B/lane gathers, 2 nodes/wave, 32 edges in flight ----------------
#define ACC8(vv, ww) { \
    float c0=__uint_as_float((vv).x<<16), c1=__uint_as_float((vv).x&0xffff0000u); \
    float c2=__uint_as_float((vv).y<<16), c3=__uint_as_float((vv).y&0xffff0000u); \
    float c4=__uint_as_float((vv).z<<16), c5=__uint_as_float((vv).z&0xffff0000u); \
    float c6=__uint_as_float((vv).w<<16), c7=__uint_as_float((vv).w&0xffff0000u); \
    s0+=c0; s1+=c1; s2+=c2; s3+=c3; s4+=c4; s5+=c5; s6+=c6; s7+=c7; \
    n0+=c0*(ww); n1+=c1*(ww); n2+=c2*(ww); n3+=c3*(ww); \
    n4+=c4*(ww); n5+=c5*(ww); n6+=c6*(ww); n7+=c7*(ww); }

template<int SHIFT>
__global__ __launch_bounds__(256) void k_aggv(const u16* h, const int* off, const int2* csr,
                                              const float* inv_sqrt, u16* out_sum, u16* out_norm, int Nn){
  int blk = xcd_swz(blockIdx.x, gridDim.x);
  int g = blk*8 + (threadIdx.x >> 5);
  if (g >= Nn) return;
  int l32 = threadIdx.x & 31;
  int sub = l32 >> 3;            // 0..3
  int cb = (l32 & 7) << 3;       // 8 channels (16B) per lane
  const u16* hp = h + cb;
  float s0=0,s1=0,s2=0,s3=0,s4=0,s5=0,s6=0,s7=0;
  float n0=0,n1=0,n2=0,n3=0,n4=0,n5=0,n6=0,n7=0;
  int e0 = off[g], e1 = off[g+1];
  int e = e0 + sub;
  for (; e + 12 < e1; e += 16){
    int2 cA = csr[e];
    int2 cB = csr[e+4];
    int2 cC = csr[e+8];
    int2 cD = csr[e+12];
    uint4 vA = *reinterpret_cast<const uint4*>(hp + (((unsigned)cA.x) << SHIFT));
    uint4 vB = *reinterpret_cast<const uint4*>(hp + (((unsigned)cB.x) << SHIFT));
    uint4 vC = *reinterpret_cast<const uint4*>(hp + (((unsigned)cC.x) << SHIFT));
    uint4 vD = *reinterpret_cast<const uint4*>(hp + (((unsigned)cD.x) << SHIFT));
    float wA = __int_as_float(cA.y), wB = __int_as_float(cB.y);
    float wC = __int_as_float(cC.y), wD = __int_as_float(cD.y);
    ACC8(vA, wA)
    ACC8(vB, wB)
    ACC8(vC, wC)
    ACC8(vD, wD)
  }
  for (; e < e1; e += 4){
    int2 cA = csr[e];
    uint4 vA = *reinterpret_cast<const uint4*>(hp + (((unsigned)cA.x) << SHIFT));
    float wA = __int_as_float(cA.y);
    ACC8(vA, wA)
  }
  #pragma unroll
  for (int m = 8; m <= 16; m <<= 1){
    s0 += __shfl_xor(s0,m,64); s1 += __shfl_xor(s1,m,64);
    s2 += __shfl_xor(s2,m,64); s3 += __shfl_xor(s3,m,64);
    s4 += __shfl_xor(s4,m,64); s5 += __shfl_xor(s5,m,64);
    s6 += __shfl_xor(s6,m,64); s7 += __shfl_xor(s7,m,64);
    n0 += __shfl_xor(n0,m,64); n1 += __shfl_xor(n1,m,64);
    n2 += __shfl_xor(n2,m,64); n3 += __shfl_xor(n3,m,64);
    n4 += __shfl_xor(n4,m,64); n5 += __shfl_xor(n5,m,64);
    n6 += __shfl_xor(n6,m,64); n7 += __shfl_xor(n7,m,64);
  }
  if (sub == 0){
    float ig = inv_sqrt[g];
    uint4 o;
    o.x = (uint)f2b(s0) | ((uint)f2b(s1) << 16);
    o.y = (uint)f2b(s2) | ((uint)f2b(s3) << 16);
    o.z = (uint)f2b(s4) | ((uint)f2b(s5) << 16);
    o.w = (uint)f2b(s6) | ((uint)f2b(s7) << 16);
    *reinterpret_cast<uint4*>(out_sum + (size_t)g*64 + cb) = o;
    o.x = (uint)f2b(n0*ig) | ((uint)f2b(n1*ig) << 16);
    o.y = (uint)f2b(n2*ig) | ((uint)f2b(n3*ig) << 16);
    o.z = (uint)f2b(n4*ig) | ((uint)f2b(n5*ig) << 16);
    o.w = (uint)f2b(n6*ig) | ((uint)f2b(n7*ig) << 16);
    *reinterpret_cast<uint4*>(out_norm + (size_t)g*64 + cb) = o;
  }
}

#define ACC8AB(va, vb, ww) { \
    float a0=__uint_as_float((va).x<<16), a1=__uint_as_float((va).x&0xffff0000u); \
    float a2=__uint_as_float((va).y<<16), a3=__uint_as_float((va).y&0xffff0000u); \
    float a4=__uint_as_float((va).z<<16), a5=__uint_as_float((va).z&0xffff0000u); \
    float a6=__uint_as_float((va).w<<16), a7=__uint_as_float((va).w&0xffff0000u); \
    float b0=__uint_as_float((vb).x<<16), b1=__uint_as_float((vb).x&0xffff0000u); \
    float b2=__uint_as_float((vb).y<<16), b3=__uint_as_float((vb).y&0xffff0000u); \
    float b4=__uint_as_float((vb).z<<16), b5=__uint_as_float((vb).z&0xffff0000u); \
    float b6=__uint_as_float((vb).w<<16), b7=__uint_as_float((vb).w&0xffff0000u); \
    sa0+=a0; sa1+=a1; sa2+=a2; sa3+=a3; sa4+=a4; sa5+=a5; sa6+=a6; sa7+=a7; \
    na0+=a0*(ww); na1+=a1*(ww); na2+=a2*(ww); na3+=a3*(ww); \
    na4+=a4*(ww); na5+=a5*(ww); na6+=a6*(ww); na7+=a7*(ww); \
    sb0+=b0; sb1+=b1; sb2+=b2; sb3+=b3; sb4+=b4; sb5+=b5; sb6+=b6; sb7+=b7; \
    nb0+=b0*(ww); nb1+=b1*(ww); nb2+=b2*(ww); nb3+=b3*(ww); \
    nb4+=b4*(ww); nb5+=b5*(ww); nb6+=b6*(ww); nb7+=b7*(ww); }

// dual-state over interleaved ab [N][128] (a at +0, b at +64); 2 nodes/wave
__global__ __launch_bounds__(256) void k_agg2v(const u16* ab, const int* off, const int2* csr,
                                               const float* inv_sqrt,
                                               u16* os0, u16* on0, u16* os1, u16* on1, int Nn){
  int blk = xcd_swz(blockIdx.x, gridDim.x);
  int g = blk*8 + (threadIdx.x >> 5);
  if (g >= Nn) return;
  int l32 = threadIdx.x & 31;
  int sub = l32 >> 3;
  int cb = (l32 & 7) << 3;
  const u16* hp = ab + cb;
  float sa0=0,sa1=0,sa2=0,sa3=0,sa4=0,sa5=0,sa6=0,sa7=0;
  float na0=0,na1=0,na2=0,na3=0,na4=0,na5=0,na6=0,na7=0;
  float sb0=0,sb1=0,sb2=0,sb3=0,sb4=0,sb5=0,sb6=0,sb7=0;
  float nb0=0,nb1=0,nb2=0,nb3=0,nb4=0,nb5=0,nb6=0,nb7=0;
  int e0 = off[g], e1 = off[g+1];
  int e = e0 + sub;
  for (; e + 4 < e1; e += 8){
    int2 cA = csr[e];
    int2 cB = csr[e+4];
    const u16* rpA = hp + (((unsigned)cA.x) << 7);
    const u16* rpB = hp + (((unsigned)cB.x) << 7);
    uint4 vaA = *reinterpret_cast<const uint4*>(rpA);
    uint4 vbA = *reinterpret_cast<const uint4*>(rpA + 64);
    uint4 vaB = *reinterpret_cast<const uint4*>(rpB);
    uint4 vbB = *reinterpret_cast<const uint4*>(rpB + 64);
    float wA = __int_as_float(cA.y), wB = __int_as_float(cB.y);
    ACC8AB(vaA, vbA, wA)
    ACC8AB(vaB, vbB, wB)
  }
  if (e < e1){
    int2 cA = csr[e];
    const u16* rpA = hp + (((unsigned)cA.x) << 7);
    uint4 vaA = *reinterpret_cast<const uint4*>(rpA);
    uint4 vbA = *reinterpret_cast<const uint4*>(rpA + 64);
    float wA = __int_as_float(cA.y);
    ACC8AB(vaA, vbA, wA)
  }
  #pragma unroll
  for (int m = 8; m <= 16; m <<= 1){
    sa0 += __shfl_xor(sa0,m,64); sa1 += __shfl_xor(sa1,m,64);
    sa2 += __shfl_xor(sa2,m,64); sa3 += __shfl_xor(sa3,m,64);
    sa4 += __shfl_xor(sa4,m,64); sa5 += __shfl_xor(sa5,m,64);
    sa6 += __shfl_xor(sa6,m,64); sa7 += __shfl_xor(sa7,m,64);
    na0 += __shfl_xor(na0,m,64); na1 += __shfl_xor(na1,m,64);
    na2 += __shfl_xor(na2,m,64); na3 += __shfl_xor(na3,m,64);
    na4 += __shfl_xor(na4,m,64); na5 += __shfl_xor(na5,m,64);
    na6 += __shfl_xor(na6,m,64); na7 += __shfl_xor(na7,m,64);
    sb0 += __shfl_xor(sb0,m,64); sb1 += __shfl_xor(sb1,m,64);
    sb2 += __shfl_xor(sb2,m,64); sb3 += __shfl_xor(sb3,m,64);
    sb4 += __shfl_xor(sb4,m,64); sb5 += __shfl_xor(sb5,m,64);
    sb6 += __shfl_xor(sb6,m,64); sb7 += __shfl_xor(sb7,m,64);
    nb0 += __shfl_xor(nb0,m,64); nb1 += __shfl_xor(nb1,m,64);
    nb2 += __shfl_xor(nb2,m,64); nb3 += __shfl_xor(nb3,m,64);
    nb4 += __shfl_xor(nb4,m,64); nb5 += __shfl_xor(nb5,m,64);
    nb6 += __shfl_xor(nb6,m,64); nb7 += __shfl_xor(nb7,m,64);
  }
  if (sub == 0){
    float ig = inv_sqrt[g];
    uint4 o;
    o.x = (uint)f2b(sa0) | ((uint)f2b(sa1) << 16);
    o.y = (uint)f2b(sa2) | ((uint)f2b(sa3) << 16);
    o.z = (uint)f2b(sa4) | ((uint)f2b(sa5) << 16);
    o.w = (uint)f2b(sa6) | ((uint)f2b(sa7) << 16);
    *reinterpret_cast<uint4*>(os0 + (size_t)g*64 + cb) = o;
    o.x = (uint)f2b(na0*ig) | ((uint)f2b(na1*ig) << 16);
    o.y = (uint)f2b(na2*ig) | ((uint)f2b(na3*ig) << 16);
    o.z = (uint)f2b(na4*ig) | ((uint)f2b(na5*ig) << 16);
    o.w = (uint)f2b(na6*ig) | ((uint)f2b(na7*ig) << 16);
    *reinterpret_cast<uint4*>(on0 + (size_t)g*64 + cb) = o;
    o.x = (uint)f2b(sb0) | ((uint)f2b(sb1) << 16);
    o.y = (uint)f2b(sb2) | ((uint)f2b(sb3) << 16);
    o.z = (uint)f2b(sb4) | ((uint)f2b(sb5) << 16);
    o.w = (uint)f2b(sb6) | ((uint)f2b(sb7) << 16);
    *reinterpret_cast<uint4*>(os1 + (size_t)g*64 + cb) = o;
    o.x = (uint)f2b(nb0*ig) | ((uint)f2b(nb1*ig) << 16);
    o.y = (uint)f2b(nb2*ig) | ((uint)f2b(nb3*ig) << 16);
    o.z = (uint)f2b(nb4*ig) | ((uint)f2b(nb5*ig) << 16);
    o.w = (uint)f2b(nb6*ig) | ((uint)f2b(nb7*ig) << 16);
    *reinterpret_cast<uint4*>(on1 + (size_t)g*64 + cb) = o;
  }
}

// ---------------- fused mixed-op step ----------------
struct StepArgs {
  const u16* h[5]; const u16* asum[5]; const u16* anorm[5];
  int rs[5]; int slot[5]; int J;
  const u16* wpk; const float* inv_deg; const u16* x0;
  u16* out; int rs_out; int Nn;
};

// 8 MFMAs of one 64x64 matrix (local idx within a 32KB half) against a
// 16-row A-fragment pair
__device__ __forceinline__ void mm8(const bh8 (&af)[2], const u16* wb, int mat,
                                    int t, int q, f4 (&acc)[4]){
  #pragma unroll
  for (int kb=0;kb<2;kb++)
    #pragma unroll
    for (int nt=0;nt<4;nt++){
      bh8 bf = ld8(wb + (mat<<12) + ((nt*16+t)<<6) + ((((kb<<2)|q) ^ (t&7))<<3));
      acc[nt] = __builtin_amdgcn_mfma_f32_16x16x32_bf16(af[kb], bf, acc[nt], 0, 0, 0);
    }
}

// ROUND-12: round-9 geometry (512 thr, 16 waves/CU via 2 blocks, 64KB LDS,
// reg-copy staging — the measured optimum) + HALF-SPLIT PIPELINE: each slot's
// 8 mats are packed as two 32KB halves (half0={1,4,5,3}: fh/fs ops;
// half1={0,6,7,2}: fn/fx/mean ops). Ping-pong: compute half0 from buf0 while
// staging half1 into buf1; barrier; compute half1 while staging next-j half0;
// barrier. Same LDS footprint & barrier count, but staging now ALSO overlaps
// this block's own compute (previously only the co-resident block covered it).
__global__ __launch_bounds__(512)
void k_step(StepArgs A){
  __shared__ __align__(16) u16 wlds[2][4*4096];   // 2 x 32 KB halves
  int tid = threadIdx.x, wv = tid>>6, lane = tid&63, q = lane>>4, t = lane&15;
  int blk = xcd_swz(blockIdx.x, gridDim.x);
  int row0 = blk*128 + wv*16;
  int rA = row0 + t;
  int q8 = q*8;
  f4 idg = *reinterpret_cast<const f4*>(A.inv_deg + row0 + q*4);
  const u16* xp = A.x0 + (size_t)rA*64;
  bh8 fx[2];
  fx[0]=ld8(xp+q8); fx[1]=ld8(xp+32+q8);

  f4 oacc[4];
  #pragma unroll
  for (int b=0;b<4;b++) oacc[b] = (f4){0.f,0.f,0.f,0.f};

  // stage one 32KB half (2048 uint4) with 512 threads: 4 chunks/thread
  auto stageH = [&](int slot, int half, int buf){
    const uint4* ws = reinterpret_cast<const uint4*>(A.wpk) + ((size_t)slot << 12) + (half<<11);
    uint4* wd = reinterpret_cast<uint4*>(&wlds[buf][0]);
    #pragma unroll
    for (int i=0;i<4;i++) wd[tid + i*512] = ws[tid + i*512];
  };

  // prologue: half0 of slot[0] -> buf0
  stageH(A.slot[0], 0, 0);
  __syncthreads();

  for (int j = 0; j < A.J; ++j){
    // ---- phase0: stage half1(j)->buf1 ; compute half0 from buf0 ----
    stageH(A.slot[j], 1, 1);

    const u16* h = A.h[j]; int rs = A.rs[j];
    const u16* hp = h + (size_t)rA*rs;
    const u16* sp = A.asum[j] + (size_t)rA*64;
    const u16* np = A.anorm[j] + (size_t)rA*64;
    bh8 fh[2], fs[2], fn[2];
    fh[0]=ld8(hp+q8); fh[1]=ld8(hp+32+q8);
    fs[0]=ld8(sp+q8); fs[1]=ld8(sp+32+q8);
    fn[0]=ld8(np+q8); fn[1]=ld8(np+32+q8);

    const u16* b0 = &wlds[0][0];
    mm8(fh, b0, 0, t, q, oacc);            // old mat1: wv3*W_self+wv5*W_gc1+wv1*I
    mm8(fs, b0, 1, t, q, oacc);            // old mat4: wv5*W_gc2 @ s_sum
    f4 p[4];
    #pragma unroll
    for (int b=0;b<4;b++) p[b] = (f4){0.f,0.f,0.f,0.f};
    mm8(fh, b0, 2, t, q, p);               // old mat5: relu(h @ wv6*W_mlp)
    #pragma unroll
    for (int nt=0;nt<4;nt++)
      #pragma unroll
      for (int r=0;r<4;r++) oacc[nt][r] += fmaxf(p[nt][r], 0.f);
    #pragma unroll
    for (int b=0;b<4;b++) p[b] = (f4){0.f,0.f,0.f,0.f};
    mm8(fh, b0, 3, t, q, p);               // old mat3: relu((h+s)@W_gin)
    mm8(fs, b0, 3, t, q, p);
    #pragma unroll
    for (int nt=0;nt<4;nt++)
      #pragma unroll
      for (int r=0;r<4;r++) oacc[nt][r] += fmaxf(p[nt][r], 0.f);

    __syncthreads();   // buf1 staged+visible; all waves done reading buf0

    // ---- phase1: stage half0(j+1)->buf0 ; compute half1 from buf1 ----
    if (j+1 < A.J) stageH(A.slot[j+1], 0, 0);

    const u16* b1 = &wlds[1][0];
    #pragma unroll
    for (int b=0;b<4;b++) p[b] = (f4){0.f,0.f,0.f,0.f};
    mm8(fn, b1, 0, t, q, p);               // old mat0: relu(s_norm @ W_gcn)
    #pragma unroll
    for (int nt=0;nt<4;nt++)
      #pragma unroll
      for (int r=0;r<4;r++) oacc[nt][r] += fmaxf(p[nt][r], 0.f);
    #pragma unroll
    for (int b=0;b<4;b++) p[b] = (f4){0.f,0.f,0.f,0.f};
    mm8(fn, b1, 1, t, q, p);               // old mat6: 0.9*wv7*W_gcnii @ sn
    mm8(fx, b1, 2, t, q, p);               // old mat7: 0.1*wv7*W_gcnii @ x0
    #pragma unroll
    for (int nt=0;nt<4;nt++)
      #pragma unroll
      for (int r=0;r<4;r++) oacc[nt][r] += fmaxf(p[nt][r], 0.f);
    #pragma unroll
    for (int b=0;b<4;b++) p[b] = (f4){0.f,0.f,0.f,0.f};
    mm8(fs, b1, 3, t, q, p);               // old mat2: inv_deg*(s_sum @ W_nei)
    #pragma unroll
    for (int nt=0;nt<4;nt++)
      #pragma unroll
      for (int r=0;r<4;r++) oacc[nt][r] += idg[r]*p[nt][r];

    if (j+1 < A.J) __syncthreads();   // buf0 staged; all waves done reading buf1
  }

  #pragma unroll
  for (int nt=0;nt<4;nt++)
    #pragma unroll
    for (int r=0;r<4;r++){
      int rr = row0 + q*4 + r;
      if (rr < A.Nn) A.out[(size_t)rr*A.rs_out + nt*16 + t] = f2b(oacc[nt][r]);
    }
}

// ---------------- classifier: MFMA GEMM [N,256]x[256,48] with bias ----------------
__global__ __launch_bounds__(256) void k_cls_mm(const u16* A, const u16* Bp,
                                                const float* bvec, float* out, int Nn){
  int tid = threadIdx.x, wv = tid>>6, lane = tid&63, q = lane>>4, t = lane&15;
  int row0 = blockIdx.x*128 + wv*32;
  f4 acc[2][3];
  #pragma unroll
  for (int a=0;a<2;a++)
    #pragma unroll
    for (int b=0;b<3;b++) acc[a][b] = (f4){0.f,0.f,0.f,0.f};
  const u16* arow0 = A + (size_t)(row0 + t)*256 + q*8;
  const u16* arow1 = arow0 + (size_t)16*256;
  const u16* brow  = Bp + (size_t)t*256 + q*8;
  #pragma unroll
  for (int kb = 0; kb < 8; ++kb){
    bh8 a0 = ld8(arow0 + kb*32);
    bh8 a1 = ld8(arow1 + kb*32);
    #pragma unroll
    for (int nt=0; nt<3; ++nt){
      bh8 bf = ld8(brow + (size_t)nt*16*256 + kb*32);
      acc[0][nt] = __builtin_amdgcn_mfma_f32_16x16x32_bf16(a0, bf, acc[0][nt], 0, 0, 0);
      acc[1][nt] = __builtin_amdgcn_mfma_f32_16x16x32_bf16(a1, bf, acc[1][nt], 0, 0, 0);
    }
  }
  #pragma unroll
  for (int rt=0;rt<2;rt++)
    #pragma unroll
    for (int nt=0;nt<3;nt++){
      int col = nt*16 + t;
      #pragma unroll
      for (int r=0;r<4;r++){
        int row = row0 + rt*16 + q*4 + r;
        if (row < Nn && col < 40) out[(size_t)row*40 + col] = acc[rt][nt][r] + bvec[col];
      }
    }
}

// ---------------- host ----------------
extern "C" void kernel_launch(void* const* d_in, const int* in_sizes, int n_in,
                              void* d_out, int out_size, void* d_ws, size_t ws_size,
                              hipStream_t stream){
  (void)n_in; (void)out_size; (void)ws_size;
  const float* x      = (const float*)d_in[0];
  const int*   ei     = (const int*)d_in[1];
  const float* alphas = (const float*)d_in[2];
  const float* stem_W = (const float*)d_in[3];
  const float* pre_W  = (const float*)d_in[4];
  const float* p00    = (const float*)d_in[5];
  const float* p10    = (const float*)d_in[6];
  const float* p01    = (const float*)d_in[7];
  const float* p11    = (const float*)d_in[8];
  const float* clsW = (const float*)d_in[17];
  const float* clsb = (const float*)d_in[18];

  int N = in_sizes[0] / 128;
  int E = in_sizes[1] / 2;
  const int* esrc = ei;
  const int* edst = ei + E;

  char* p = (char*)d_ws;
  auto carve = [&](size_t bytes) -> char* {
    char* r = p; p += (bytes + 255) & ~(size_t)255; return r;
  };
  int*   hist    = (int*)carve((size_t)NBK*4);
  int*   bbase   = (int*)carve((size_t)(NBK+1)*4);
  int*   bcursor = (int*)carve((size_t)NBK*4);
  unsigned* bkt  = (unsigned*)carve((size_t)E*4);
  int*   off     = (int*)carve((size_t)(N+1)*4);
  int2*  csr     = (int2*)carve((size_t)E*8);
  float* inv_deg = (float*)carve((size_t)N*4);
  float* invs    = (float*)carve((size_t)N*4);
  float* wmix    = (float*)carve(14*8*4);
  float* stats   = (float*)carve(512*4);
  float* Sp      = (float*)carve((size_t)512*512*4);   // per-block partial stats
  u16* xb      = (u16*)carve((size_t)N*128*2);
  u16* spk     = (u16*)carve((size_t)256*128*2);       // fused stem(192)+pre(64) weights
  u16* p00_pk  = (u16*)carve((size_t)64*192*2);
  u16* p10_pk  = (u16*)carve((size_t)64*192*2);
  u16* p01_pk  = (u16*)carve((size_t)64*192*2);
  u16* p11_pk  = (u16*)carve((size_t)64*256*2);
  u16* cls_pk  = (u16*)carve((size_t)48*256*2);
  u16* ops_pk  = (u16*)carve((size_t)28*8*4096*2);
  u16* T       = (u16*)carve((size_t)N*256*2);
  u16* stem_o  = (u16*)carve((size_t)N*192*2);
  u16* x0b     = (u16*)carve((size_t)N*64*2);
  u16* ab      = (u16*)carve((size_t)N*128*2);
  u16* oc0     = (u16*)carve((size_t)N*256*2);
  u16* oc1     = (u16*)carve((size_t)N*256*2);
  u16* agg     = (u16*)carve((size_t)5*2*N*64*2);
  carve(262144); // tail slack for unguarded OOB-row reads

  auto aggS = [&](int j){ return agg + (size_t)j*2*N*64; };
  auto aggN = [&](int j){ return agg + (size_t)j*2*N*64 + (size_t)N*64; };

  int NB = (N + 127)/128;        // real buckets
  int gg = (N + 127)/128;
  int gstep = (N + 127)/128;     // 391 blocks -> 2 per CU
  int ag = (N + 7)/8;            // 8 nodes/block (2 per wave)
  float invN = 1.0f/(float)N;

  // ---- CSR build (bucketed) ----
  hipMemsetAsync(hist, 0, (size_t)NBK*4, stream);
  k_hist<<<256,256,0,stream>>>(edst, hist, E);
  k_scanb<<<1,512,0,stream>>>(hist, bbase, bcursor);
  k_bucket<<<256,256,0,stream>>>(esrc, edst, bcursor, bkt, E, 256);
  k_degb<<<NB,128,0,stream>>>(bkt, bbase, off, inv_deg, invs, N, E);
  k_fillb<<<NB,128,0,stream>>>(bkt, bbase, off, invs, csr, N);

  k_softmax<<<1,128,0,stream>>>(alphas, wmix);
  k_f2b<<<(N*128+255)/256,256,0,stream>>>(x, xb, N*128);

  // all weight packs in ONE launch
  {
    PackAllArgs PA;
    PA.src[0]=stem_W; PA.dst[0]=spk;          PA.K[0]=128; PA.ncol[0]=192;  // stem -> spk rows 0-191
    PA.src[1]=pre_W;  PA.dst[1]=spk+192*128;  PA.K[1]=128; PA.ncol[1]=64;   // pre  -> spk rows 192-255
    PA.src[2]=p00;    PA.dst[2]=p00_pk;       PA.K[2]=192; PA.ncol[2]=64;
    PA.src[3]=p10;    PA.dst[3]=p10_pk;       PA.K[3]=192; PA.ncol[3]=64;
    PA.src[4]=p01;    PA.dst[4]=p01_pk;       PA.K[4]=192; PA.ncol[4]=64;
    PA.src[5]=p11;    PA.dst[5]=p11_pk;       PA.K[5]=256; PA.ncol[5]=64;
    PA.src[6]=clsW;   PA.dst[6]=cls_pk;
    PA.K[6]=0; PA.ncol[6]=0;
    int b = 0;
    PA.base[0]=0;
    int sizes[7] = {128*192, 128*64, 192*64, 192*64, 192*64, 256*64, 48*256};
    for (int s=0;s<7;s++){ b += sizes[s]; PA.base[s+1]=b; }
    k_packall<<<(b+255)/256,256,0,stream>>>(PA);
  }
  {
    PackArgs PA;
    for (int i = 0; i < 8; ++i) PA.W[i] = (const float*)d_in[9+i];
    PA.wmix = wmix; PA.dst = ops_pk;
    k_pack_ops8<<<(28*8*4096+255)/256,256,0,stream>>>(PA);
  }

  // mlp: GEMM (per-block partials) -> redstats -> norm. K/ncol compile-time.
  auto mlp = [&](const u16* A, int K, const u16* Bp, int ncol, u16* outb, int rs_out, int relu){
    if (K == 192)
      hipLaunchKernelGGL(HIP_KERNEL_NAME(k_gemm<4,6>), dim3(gg), dim3(256), 0, stream, A, Bp, T, N, Sp);
    else
      hipLaunchKernelGGL(HIP_KERNEL_NAME(k_gemm<4,8>), dim3(gg), dim3(256), 0, stream, A, Bp, T, N, Sp);
    k_redstats<<<(2*ncol+3)/4,256,0,stream>>>(Sp, stats, ncol, gg);
    k_norm<<<((N*(ncol>>3))+255)/256,256,0,stream>>>(T, ncol, ncol, N, stats, outb, rs_out, relu, invN);
  };

  // fused stem (192 cols, no relu) + preprocess (64 cols, relu): one GEMM over xb
  hipLaunchKernelGGL(HIP_KERNEL_NAME(k_gemm<16,4>), dim3(gg), dim3(256), 0, stream, xb, spk, T, N, Sp);
  k_redstats<<<(512+3)/4,256,0,stream>>>(Sp, stats, 256, gg);
  k_norm2<<<(N*32+255)/256,256,0,stream>>>(T, N, stats, stem_o, x0b, invN);

  u16* ocs[2] = {oc0, oc1};
  const int slotbase[4] = {0, 2, 5, 9};
  for (int ci = 0; ci < 2; ++ci){
    const u16* s1in = (ci == 0) ? stem_o : oc0;
    int Kb   = (ci == 0) ? 192 : 256;
    const u16* pa = (ci == 0) ? p00_pk : p01_pk;
    const u16* pb = (ci == 0) ? p10_pk : p11_pk;
    mlp(stem_o, 192, pa, 64, ab, 128, 1);        // a -> ab[:, 0:64]
    mlp(s1in, Kb, pb, 64, ab + 64, 128, 1);      // b -> ab[:, 64:128]

    u16* oc = ocs[ci];
    const u16* wpk_cell = ops_pk + (size_t)ci*14*8*4096;

    k_agg2v<<<ag,256,0,stream>>>(ab, off, csr, invs,
                                 aggS(0), aggN(0), aggS(1), aggN(1), N);

    const u16* st[5] = { ab, ab + 64, oc + 0, oc + 64, oc + 128 };
    const int strs[5] = {128, 128, 256, 256, 256};
    for (int step = 0; step < 4; ++step){
      StepArgs SA{};
      int J = step + 2;
      for (int j = 0; j < J; ++j){
        SA.h[j] = st[j]; SA.rs[j] = strs[j];
        SA.asum[j] = aggS(j); SA.anorm[j] = aggN(j);
        SA.slot[j] = slotbase[step] + j;
      }
      SA.J = J; SA.wpk = wpk_cell; SA.inv_deg = inv_deg; SA.x0 = x0b;
      SA.out = oc + (size_t)step*64; SA.rs_out = 256; SA.Nn = N;
      k_step<<<gstep,512,0,stream>>>(SA);
      if (step < 3)
        hipLaunchKernelGGL(HIP_KERNEL_NAME(k_aggv<8>), dim3(ag), dim3(256), 0, stream,
                           oc + (size_t)step*64, off, csr, invs, aggS(step+2), aggN(step+2), N);
    }
  }

  k_cls_mm<<<gg,256,0,stream>>>(oc1, cls_pk, clsb, (float*)d_out, N);
}

// Round 13
// 774.356 us; speedup vs baseline: 1.0074x; 1.0074x over previous
//
#include <hip/hip_runtime.h>
#include <stdint.h>

typedef unsigned short u16;
typedef __attribute__((ext_vector_type(8))) short bh8;   // 8 x bf16 (bits)
typedef __attribute__((ext_vector_type(4))) float f4;

__device__ __forceinline__ float b2f(u16 u){ union{unsigned u; float f;} x; x.u = ((unsigned)u)<<16; return x.f; }
__device__ __forceinline__ u16 f2b(float f){ union{float f; unsigned u;} x; x.f = f; return (u16)((x.u + 0x7fffu + ((x.u>>16)&1u))>>16); }
__device__ __forceinline__ bh8 ld8(const u16* p){ return *reinterpret_cast<const bh8*>(p); }

// bijective XCD-chunked block swizzle (m204 form)
__device__ __forceinline__ int xcd_swz(int bid, int nwg){
  int q = nwg >> 3, r = nwg & 7;
  int x = bid & 7, k = bid >> 3;
  return (x < r ? x*(q+1) : r*(q+1) + (x - r)*q) + k;
}

// ---------------- graph preprocessing: bucketed counting-sort CSR build ----------------
#define NBK 512   // bucket slots (real buckets = ceil(N/128) <= 391)

__global__ __launch_bounds__(256) void k_hist(const int* dst, int* hist, int E){
  __shared__ int h[NBK];
  for (int i=threadIdx.x;i<NBK;i+=256) h[i]=0;
  __syncthreads();
  int stride = 256*gridDim.x;
  for (int i = blockIdx.x*256+threadIdx.x; i<E; i+=stride)
    atomicAdd(&h[dst[i]>>7], 1);
  __syncthreads();
  for (int i=threadIdx.x;i<NBK;i+=256){
    int v=h[i]; if (v) atomicAdd(&hist[i], v);
  }
}

__global__ __launch_bounds__(512) void k_scanb(const int* hist, int* bbase, int* bcursor){
  int t = threadIdx.x, lane = t&63, wv = t>>6;
  __shared__ int ws[8];
  int v = hist[t];
  int x = v;
  #pragma unroll
  for (int o=1;o<64;o<<=1){ int u=__shfl_up(x,(unsigned)o,64); if(lane>=o) x+=u; }
  if (lane==63) ws[wv]=x;
  __syncthreads();
  if (t<8){
    int s=ws[t];
    #pragma unroll
    for (int o=1;o<8;o<<=1){ int u=__shfl_up(s,(unsigned)o,8); if (t>=o) s+=u; }
    ws[t]=s;
  }
  __syncthreads();
  int base = (wv==0)?0:ws[wv-1];
  int ex = base + x - v;
  bbase[t]=ex; bcursor[t]=ex;
  if (t==511) bbase[512]=ex+v;
}

__global__ __launch_bounds__(256) void k_bucket(const int* src, const int* dst,
                                                int* bcursor, unsigned* bkt, int E, int nblk){
  __shared__ int h[NBK], base[NBK], lc[NBK];
  int per = (E + nblk - 1)/nblk;
  int e0 = blockIdx.x*per, e1 = min(E, e0+per);
  for (int i=threadIdx.x;i<NBK;i+=256){ h[i]=0; lc[i]=0; }
  __syncthreads();
  for (int e=e0+threadIdx.x; e<e1; e+=256) atomicAdd(&h[dst[e]>>7], 1);
  __syncthreads();
  for (int i=threadIdx.x;i<NBK;i+=256){
    int c=h[i]; base[i] = c ? atomicAdd(&bcursor[i], c) : 0;
  }
  __syncthreads();
  for (int e=e0+threadIdx.x; e<e1; e+=256){
    int d = dst[e];
    int b = d>>7;
    int r = atomicAdd(&lc[b], 1);
    bkt[base[b]+r] = ((unsigned)(d&127)<<25) | (unsigned)src[e];
  }
}

__global__ __launch_bounds__(128) void k_degb(const unsigned* bkt, const int* bbase,
                                              int* off, float* inv_deg, float* invs,
                                              int N, int E){
  int b = blockIdx.x, t = threadIdx.x;
  __shared__ int cnt[128];
  __shared__ int w0tot;
  cnt[t]=0;
  __syncthreads();
  int e0=bbase[b], e1=bbase[b+1];
  for (int e=e0+t; e<e1; e+=128) atomicAdd(&cnt[bkt[e]>>25], 1);
  __syncthreads();
  int v = cnt[t];
  int lane=t&63, wv=t>>6;
  int x=v;
  #pragma unroll
  for (int o=1;o<64;o<<=1){ int u=__shfl_up(x,(unsigned)o,64); if(lane>=o) x+=u; }
  if (t==63) w0tot=x;
  __syncthreads();
  int ex = x - v + (wv ? w0tot : 0);
  int node = b*128 + t;
  if (node < N){
    off[node] = e0 + ex;
    int d = (v<1)?1:v;
    float df=(float)d;
    inv_deg[node]=1.0f/df;
    invs[node]=rsqrtf(df);
  }
  if (b==0 && t==0) off[N]=E;
}

__global__ __launch_bounds__(128) void k_fillb(const unsigned* bkt, const int* bbase,
                                               const int* off, const float* invs,
                                               int2* csr, int N){
  int b = blockIdx.x, t = threadIdx.x;
  __shared__ int cur[128];
  int node = b*128 + t;
  cur[t] = (node < N) ? off[node] : 0;
  __syncthreads();
  int e0=bbase[b], e1=bbase[b+1];
  for (int e=e0+t; e<e1; e+=128){
    unsigned v = bkt[e];
    int i = (int)(v>>25);
    int s = (int)(v & 0x1FFFFFFu);
    int pos = atomicAdd(&cur[i], 1);
    csr[pos] = make_int2(s, __float_as_int(invs[s]));
  }
}

__global__ void k_softmax(const float* alphas, float* wmix){
  int t = threadIdx.x; int r = t >> 3, o = t & 7;
  if (r < 14){
    float v = alphas[r*8+o];
    float m = v;
    #pragma unroll
    for (int d=1; d<8; d<<=1) m = fmaxf(m, __shfl_xor(m, d, 8));
    float e = expf(v - m);
    float s = e;
    #pragma unroll
    for (int d=1; d<8; d<<=1) s += __shfl_xor(s, d, 8);
    wmix[r*8+o] = e / s;
  }
}

// ---------------- conversion / packing ----------------
__global__ void k_f2b(const float* a, u16* b, int n){
  int i = blockIdx.x*256 + threadIdx.x;
  if (i < n) b[i] = f2b(a[i]);
}

// all 7 weight-pack jobs in one launch (segmented index space).
struct PackAllArgs {
  const float* src[7];
  u16* dst[7];
  int K[7], ncol[7];
  int base[8];
};
__global__ __launch_bounds__(256) void k_packall(PackAllArgs P){
  int i = blockIdx.x*256 + threadIdx.x;
  if (i >= P.base[7]) return;
  int s = 0;
  #pragma unroll
  for (int k=1;k<7;k++) if (i >= P.base[k]) s = k;
  int e = i - P.base[s];
  if (s < 6){
    int K = P.K[s], ncol = P.ncol[s];
    int k = e / ncol, n = e - k*ncol;
    P.dst[s][(size_t)n*K + k] = f2b(P.src[s][e]);
  } else {
    int n = e >> 8, k = e & 255;
    float v = 0.f;
    if (n < 40) v = P.src[6][(size_t)(1+k)*40 + n] + P.src[6][n] * (1.f/256.f);
    P.dst[6][(size_t)n*256 + k] = f2b(v);
  }
}

// op weights with softmax-mix folding; 8 matrices per slot.
// mats PERMUTED into two contiguous 32KB halves by consumer:
//   half0 (positions 0-3) = old {1,4,5,3}  (fh/fs consumers)
//   half1 (positions 4-7) = old {0,6,7,2}  (fn/fx/mean consumers)
// dst layout [n][k] with the k_step XOR-swizzle baked in.
struct PackArgs { const float* W[8]; const float* wmix; u16* dst; };
__global__ void k_pack_ops8(PackArgs P){
  int i = blockIdx.x*256 + threadIdx.x;
  if (i >= 28*8*4096) return;
  int slot28 = i >> 15;
  int rem = i & 32767;
  int mat = rem >> 12;
  int e = rem & 4095;
  int k = e >> 6, n = e & 63;
  const float* wm = P.wmix + (slot28 % 14)*8;
  size_t off = (size_t)slot28*4096 + e;   // source [28][64][64] row-major [k][n]
  float v = 0.f;
  switch(mat){
    case 0: v = wm[2]*P.W[0][off]; break;
    case 1: v = wm[3]*P.W[1][off] + wm[5]*P.W[4][off] + ((k==n) ? wm[1] : 0.f); break;
    case 2: v = wm[3]*P.W[2][off]; break;
    case 3: v = wm[4]*P.W[3][off]; break;
    case 4: v = wm[5]*P.W[5][off]; break;
    case 5: v = wm[6]*P.W[6][off]; break;
    case 6: v = 0.9f*wm[7]*P.W[7][off]; break;
    case 7: v = 0.1f*wm[7]*P.W[7][off]; break;
  }
  const int perm[8] = {4,0,7,3,1,2,5,6};   // old mat id -> packed position
  P.dst[(((size_t)slot28*8 + perm[mat])<<12) + (n<<6) + (((k>>3) ^ (n&7))<<3) + (k&7)] = f2b(v);
}

// ---------------- MLP: GEMM + per-block partial stats (no global atomics) ----------------
template<int NT, int NKB>
__global__ __launch_bounds__(256) void k_gemm(const u16* A, const u16* Bp,
                                              u16* Tb, int Nn, float* Sp){
  const int K = NKB*32;
  const int ldT = NT*16;
  __shared__ float sred[4][NT*16][2];
  int tid = threadIdx.x, wv = tid>>6, lane = tid&63, q = lane>>4, t = lane&15;
  int row0 = blockIdx.x*128 + wv*32;
  f4 acc[2][NT];
  #pragma unroll
  for (int a=0;a<2;a++)
    #pragma unroll
    for (int b=0;b<NT;b++) acc[a][b] = (f4){0.f,0.f,0.f,0.f};
  const u16* arow0 = A + (size_t)(row0 + t)*K + q*8;
  const u16* arow1 = arow0 + (size_t)16*K;
  const u16* brow  = Bp + (size_t)t*K + q*8;
  #pragma unroll
  for (int kb = 0; kb < NKB; ++kb){
    bh8 a0 = ld8(arow0 + kb*32);
    bh8 a1 = ld8(arow1 + kb*32);
    #pragma unroll
    for (int nt=0; nt<NT; ++nt){
      bh8 bf = ld8(brow + (size_t)nt*16*K + kb*32);
      acc[0][nt] = __builtin_amdgcn_mfma_f32_16x16x32_bf16(a0, bf, acc[0][nt], 0, 0, 0);
      acc[1][nt] = __builtin_amdgcn_mfma_f32_16x16x32_bf16(a1, bf, acc[1][nt], 0, 0, 0);
    }
  }
  #pragma unroll
  for (int nt=0;nt<NT;nt++){
    float ps = 0.f, pq = 0.f;
    #pragma unroll
    for (int rt=0;rt<2;rt++)
      #pragma unroll
      for (int r=0;r<4;r++){
        int row = row0 + rt*16 + q*4 + r;
        float v = acc[rt][nt][r];
        if (row < Nn){
          Tb[(size_t)row*ldT + nt*16 + t] = f2b(v);
          ps += v; pq += v*v;
        }
      }
    ps += __shfl_xor(ps, 16, 64); pq += __shfl_xor(pq, 16, 64);
    ps += __shfl_xor(ps, 32, 64); pq += __shfl_xor(pq, 32, 64);
    if (q == 0){ sred[wv][nt*16 + t][0] = ps; sred[wv][nt*16 + t][1] = pq; }
  }
  __syncthreads();
  if (tid < NT*16){
    float s = sred[0][tid][0] + sred[1][tid][0] + sred[2][tid][0] + sred[3][tid][0];
    float qq = sred[0][tid][1] + sred[1][tid][1] + sred[2][tid][1] + sred[3][tid][1];
    float* sp = Sp + (size_t)blockIdx.x*(2*NT*16);
    sp[tid] = s;
    sp[NT*16 + tid] = qq;        // coalesced plain stores, no contention
  }
}

// ROUND-13: fused stem+pre GEMM, COLUMN-SPLIT. Round-12's k_gemm<16,4>
// regressed to 62us (VGPR 156 = acc[2][16] at a waves/SIMD cliff, 128
// scalar stores/thread epilogue, occupancy 9%). grid (gg,2): blockIdx.y
// picks a 128-col half; NT=8 -> acc 64 VGPR, half the epilogue, 2x blocks.
// Stats partials: region (bx*2+by)*256: [0..127]=sum, [128..255]=sumsq.
__global__ __launch_bounds__(256) void k_gemm2(const u16* A, const u16* Bp,
                                               u16* Tb, int Nn, float* Sp){
  const int K = 128;
  __shared__ float sred[4][128][2];
  int tid = threadIdx.x, wv = tid>>6, lane = tid&63, q = lane>>4, t = lane&15;
  int row0 = blockIdx.x*128 + wv*32;
  int cb0 = blockIdx.y << 7;
  f4 acc[2][8];
  #pragma unroll
  for (int a=0;a<2;a++)
    #pragma unroll
    for (int b=0;b<8;b++) acc[a][b] = (f4){0.f,0.f,0.f,0.f};
  const u16* arow0 = A + (size_t)(row0 + t)*K + q*8;
  const u16* arow1 = arow0 + (size_t)16*K;
  const u16* brow  = Bp + (size_t)(cb0 + t)*K + q*8;
  #pragma unroll
  for (int kb = 0; kb < 4; ++kb){
    bh8 a0 = ld8(arow0 + kb*32);
    bh8 a1 = ld8(arow1 + kb*32);
    #pragma unroll
    for (int nt=0; nt<8; ++nt){
      bh8 bf = ld8(brow + (size_t)nt*16*K + kb*32);
      acc[0][nt] = __builtin_amdgcn_mfma_f32_16x16x32_bf16(a0, bf, acc[0][nt], 0, 0, 0);
      acc[1][nt] = __builtin_amdgcn_mfma_f32_16x16x32_bf16(a1, bf, acc[1][nt], 0, 0, 0);
    }
  }
  #pragma unroll
  for (int nt=0;nt<8;nt++){
    float ps = 0.f, pq = 0.f;
    #pragma unroll
    for (int rt=0;rt<2;rt++)
      #pragma unroll
      for (int r=0;r<4;r++){
        int row = row0 + rt*16 + q*4 + r;
        float v = acc[rt][nt][r];
        if (row < Nn){
          Tb[(size_t)row*256 + cb0 + nt*16 + t] = f2b(v);
          ps += v; pq += v*v;
        }
      }
    ps += __shfl_xor(ps, 16, 64); pq += __shfl_xor(pq, 16, 64);
    ps += __shfl_xor(ps, 32, 64); pq += __shfl_xor(pq, 32, 64);
    if (q == 0){ sred[wv][nt*16 + t][0] = ps; sred[wv][nt*16 + t][1] = pq; }
  }
  __syncthreads();
  if (tid < 128){
    float s = sred[0][tid][0] + sred[1][tid][0] + sred[2][tid][0] + sred[3][tid][0];
    float qq = sred[0][tid][1] + sred[1][tid][1] + sred[2][tid][1] + sred[3][tid][1];
    float* sp = Sp + ((size_t)blockIdx.x*2 + blockIdx.y)*256;
    sp[tid] = s;
    sp[128 + tid] = qq;
  }
}

// reduce per-block partials -> S[c] (sum), S[256+c] (sumsq).
__global__ __launch_bounds__(256) void k_redstats(const float* Sp, float* S, int ncol, int nb){
  int c2 = blockIdx.x*4 + (threadIdx.x>>6);
  int lane = threadIdx.x & 63;
  if (c2 >= 2*ncol) return;
  int stride = 2*ncol;
  float s = 0.f;
  for (int b = lane; b < nb; b += 64) s += Sp[(size_t)b*stride + c2];
  #pragma unroll
  for (int m=1; m<64; m<<=1) s += __shfl_xor(s, m, 64);
  if (lane == 0){
    int c = (c2 < ncol) ? c2 : (256 + (c2 - ncol));
    S[c] = s;
  }
}

// redstats for k_gemm2's (bx,by)-segmented layout; 256 cols.
__global__ __launch_bounds__(256) void k_redstats2(const float* Sp, float* S, int nb){
  int c2 = blockIdx.x*4 + (threadIdx.x>>6);
  int lane = threadIdx.x & 63;
  if (c2 >= 512) return;
  int issum = (c2 < 256);
  int c = issum ? c2 : (c2 - 256);
  int by = c >> 7, idx = c & 127;
  const float* base = Sp + (size_t)by*256 + (issum ? 0 : 128) + idx;
  float s = 0.f;
  for (int b = lane; b < nb; b += 64) s += base[(size_t)b*512];
  #pragma unroll
  for (int m=1; m<64; m<<=1) s += __shfl_xor(s, m, 64);
  if (lane == 0) S[issum ? c : 256 + c] = s;
}

__global__ void k_norm(const u16* Tb, int ldT, int ncols, int Nn, const float* S,
                       u16* out, int rs_out, int relu, float invN){
  int i = blockIdx.x*256 + threadIdx.x;
  int nv = ncols >> 3;
  if (i >= Nn*nv) return;
  int r = i / nv, c8 = (i - r*nv)*8;
  bh8 tv = ld8(Tb + (size_t)r*ldT + c8);
  bh8 ov;
  #pragma unroll
  for (int u=0; u<8; ++u){
    int c = c8 + u;
    float m = S[c]*invN;
    float var = S[256+c]*invN - m*m;
    float xv = (b2f((u16)tv[u]) - m) * rsqrtf(var + 1e-5f);
    if (relu) xv = fmaxf(xv, 0.f);
    ov[u] = (short)f2b(xv);
  }
  *reinterpret_cast<bh8*>(out + (size_t)r*rs_out + c8) = ov;
}

// split-output norm for the fused stem+pre GEMM (256 cols in T):
// cols 0-191 -> stem_o (no relu, stride 192); cols 192-255 -> x0b (relu, stride 64)
__global__ void k_norm2(const u16* Tb, int Nn, const float* S,
                        u16* o1, u16* o2, float invN){
  int i = blockIdx.x*256 + threadIdx.x;
  if (i >= Nn*32) return;
  int r = i >> 5, c8 = (i & 31) << 3;
  bh8 tv = ld8(Tb + (size_t)r*256 + c8);
  bh8 ov;
  int relu = (c8 >= 192);
  #pragma unroll
  for (int u=0; u<8; ++u){
    int c = c8 + u;
    float m = S[c]*invN;
    float var = S[256+c]*invN - m*m;
    float xv = (b2f((u16)tv[u]) - m) * rsqrtf(var + 1e-5f);
    if (relu) xv = fmaxf(xv, 0.f);
    ov[u] = (short)f2b(xv);
  }
  if (c8 < 192)
    *reinterpret_cast<bh8*>(o1 + (size_t)r*192 + c8) = ov;
  else
    *reinterpret_cast<bh8*>(o2 + (size_t)r*64 + (c8 - 192)) = ov;
}

// ---------------- aggregation: 16B/lane gathers, 2 nodes/wave, 32 edges in flight ----------------
#define ACC8(vv, ww) { \
    float c0=__uint_as_float((vv).x<<16), c1=__uint_as_float((vv).x&0xffff0000u); \
    float c2=__uint_as_float((vv).y<<16), c3=__uint_as_float((vv).y&0xffff0000u); \
    float c4=__uint_as_float((vv).z<<16), c5=__uint_as_float((vv).z&0xffff0000u); \
    float c6=__uint_as_float((vv).w<<16), c7=__uint_as_float((vv).w&0xffff0000u); \
    s0+=c0; s1+=c1; s2+=c2; s3+=c3; s4+=c4; s5+=c5; s6+=c6; s7+=c7; \
    n0+=c0*(ww); n1+=c1*(ww); n2+=c2*(ww); n3+=c3*(ww); \
    n4+=c4*(ww); n5+=c5*(ww); n6+=c6*(ww); n7+=c7*(ww); }

template<int SHIFT>
__global__ __launch_bounds__(256) void k_aggv(const u16* h, const int* off, const int2* csr,
                                              const float* inv_sqrt, u16* out_sum, u16* out_norm, int Nn){
  int blk = xcd_swz(blockIdx.x, gridDim.x);
  int g = blk*8 + (threadIdx.x >> 5);
  if (g >= Nn) return;
  int l32 = threadIdx.x & 31;
  int sub = l32 >> 3;            // 0..3
  int cb = (l32 & 7) << 3;       // 8 channels (16B) per lane
  const u16* hp = h + cb;
  float s0=0,s1=0,s2=0,s3=0,s4=0,s5=0,s6=0,s7=0;
  float n0=0,n1=0,n2=0,n3=0,n4=0,n5=0,n6=0,n7=0;
  int e0 = off[g], e1 = off[g+1];
  int e = e0 + sub;
  for (; e + 12 < e1; e += 16){
    int2 cA = csr[e];
    int2 cB = csr[e+4];
    int2 cC = csr[e+8];
    int2 cD = csr[e+12];
    uint4 vA = *reinterpret_cast<const uint4*>(hp + (((unsigned)cA.x) << SHIFT));
    uint4 vB = *reinterpret_cast<const uint4*>(hp + (((unsigned)cB.x) << SHIFT));
    uint4 vC = *reinterpret_cast<const uint4*>(hp + (((unsigned)cC.x) << SHIFT));
    uint4 vD = *reinterpret_cast<const uint4*>(hp + (((unsigned)cD.x) << SHIFT));
    float wA = __int_as_float(cA.y), wB = __int_as_float(cB.y);
    float wC = __int_as_float(cC.y), wD = __int_as_float(cD.y);
    ACC8(vA, wA)
    ACC8(vB, wB)
    ACC8(vC, wC)
    ACC8(vD, wD)
  }
  for (; e < e1; e += 4){
    int2 cA = csr[e];
    uint4 vA = *reinterpret_cast<const uint4*>(hp + (((unsigned)cA.x) << SHIFT));
    float wA = __int_as_float(cA.y);
    ACC8(vA, wA)
  }
  #pragma unroll
  for (int m = 8; m <= 16; m <<= 1){
    s0 += __shfl_xor(s0,m,64); s1 += __shfl_xor(s1,m,64);
    s2 += __shfl_xor(s2,m,64); s3 += __shfl_xor(s3,m,64);
    s4 += __shfl_xor(s4,m,64); s5 += __shfl_xor(s5,m,64);
    s6 += __shfl_xor(s6,m,64); s7 += __shfl_xor(s7,m,64);
    n0 += __shfl_xor(n0,m,64); n1 += __shfl_xor(n1,m,64);
    n2 += __shfl_xor(n2,m,64); n3 += __shfl_xor(n3,m,64);
    n4 += __shfl_xor(n4,m,64); n5 += __shfl_xor(n5,m,64);
    n6 += __shfl_xor(n6,m,64); n7 += __shfl_xor(n7,m,64);
  }
  if (sub == 0){
    float ig = inv_sqrt[g];
    uint4 o;
    o.x = (uint)f2b(s0) | ((uint)f2b(s1) << 16);
    o.y = (uint)f2b(s2) | ((uint)f2b(s3) << 16);
    o.z = (uint)f2b(s4) | ((uint)f2b(s5) << 16);
    o.w = (uint)f2b(s6) | ((uint)f2b(s7) << 16);
    *reinterpret_cast<uint4*>(out_sum + (size_t)g*64 + cb) = o;
    o.x = (uint)f2b(n0*ig) | ((uint)f2b(n1*ig) << 16);
    o.y = (uint)f2b(n2*ig) | ((uint)f2b(n3*ig) << 16);
    o.z = (uint)f2b(n4*ig) | ((uint)f2b(n5*ig) << 16);
    o.w = (uint)f2b(n6*ig) | ((uint)f2b(n7*ig) << 16);
    *reinterpret_cast<uint4*>(out_norm + (size_t)g*64 + cb) = o;
  }
}

#define ACC8AB(va, vb, ww) { \
    float a0=__uint_as_float((va).x<<16), a1=__uint_as_float((va).x&0xffff0000u); \
    float a2=__uint_as_float((va).y<<16), a3=__uint_as_float((va).y&0xffff0000u); \
    float a4=__uint_as_float((va).z<<16), a5=__uint_as_float((va).z&0xffff0000u); \
    float a6=__uint_as_float((va).w<<16), a7=__uint_as_float((va).w&0xffff0000u); \
    float b0=__uint_as_float((vb).x<<16), b1=__uint_as_float((vb).x&0xffff0000u); \
    float b2=__uint_as_float((vb).y<<16), b3=__uint_as_float((vb).y&0xffff0000u); \
    float b4=__uint_as_float((vb).z<<16), b5=__uint_as_float((vb).z&0xffff0000u); \
    float b6=__uint_as_float((vb).w<<16), b7=__uint_as_float((vb).w&0xffff0000u); \
    sa0+=a0; sa1+=a1; sa2+=a2; sa3+=a3; sa4+=a4; sa5+=a5; sa6+=a6; sa7+=a7; \
    na0+=a0*(ww); na1+=a1*(ww); na2+=a2*(ww); na3+=a3*(ww); \
    na4+=a4*(ww); na5+=a5*(ww); na6+=a6*(ww); na7+=a7*(ww); \
    sb0+=b0; sb1+=b1; sb2+=b2; sb3+=b3; sb4+=b4; sb5+=b5; sb6+=b6; sb7+=b7; \
    nb0+=b0*(ww); nb1+=b1*(ww); nb2+=b2*(ww); nb3+=b3*(ww); \
    nb4+=b4*(ww); nb5+=b5*(ww); nb6+=b6*(ww); nb7+=b7*(ww); }

// dual-state over interleaved ab [N][128] (a at +0, b at +64); 2 nodes/wave
__global__ __launch_bounds__(256) void k_agg2v(const u16* ab, const int* off, const int2* csr,
                                               const float* inv_sqrt,
                                               u16* os0, u16* on0, u16* os1, u16* on1, int Nn){
  int blk = xcd_swz(blockIdx.x, gridDim.x);
  int g = blk*8 + (threadIdx.x >> 5);
  if (g >= Nn) return;
  int l32 = threadIdx.x & 31;
  int sub = l32 >> 3;
  int cb = (l32 & 7) << 3;
  const u16* hp = ab + cb;
  float sa0=0,sa1=0,sa2=0,sa3=0,sa4=0,sa5=0,sa6=0,sa7=0;
  float na0=0,na1=0,na2=0,na3=0,na4=0,na5=0,na6=0,na7=0;
  float sb0=0,sb1=0,sb2=0,sb3=0,sb4=0,sb5=0,sb6=0,sb7=0;
  float nb0=0,nb1=0,nb2=0,nb3=0,nb4=0,nb5=0,nb6=0,nb7=0;
  int e0 = off[g], e1 = off[g+1];
  int e = e0 + sub;
  for (; e + 4 < e1; e += 8){
    int2 cA = csr[e];
    int2 cB = csr[e+4];
    const u16* rpA = hp + (((unsigned)cA.x) << 7);
    const u16* rpB = hp + (((unsigned)cB.x) << 7);
    uint4 vaA = *reinterpret_cast<const uint4*>(rpA);
    uint4 vbA = *reinterpret_cast<const uint4*>(rpA + 64);
    uint4 vaB = *reinterpret_cast<const uint4*>(rpB);
    uint4 vbB = *reinterpret_cast<const uint4*>(rpB + 64);
    float wA = __int_as_float(cA.y), wB = __int_as_float(cB.y);
    ACC8AB(vaA, vbA, wA)
    ACC8AB(vaB, vbB, wB)
  }
  if (e < e1){
    int2 cA = csr[e];
    const u16* rpA = hp + (((unsigned)cA.x) << 7);
    uint4 vaA = *reinterpret_cast<const uint4*>(rpA);
    uint4 vbA = *reinterpret_cast<const uint4*>(rpA + 64);
    float wA = __int_as_float(cA.y);
    ACC8AB(vaA, vbA, wA)
  }
  #pragma unroll
  for (int m = 8; m <= 16; m <<= 1){
    sa0 += __shfl_xor(sa0,m,64); sa1 += __shfl_xor(sa1,m,64);
    sa2 += __shfl_xor(sa2,m,64); sa3 += __shfl_xor(sa3,m,64);
    sa4 += __shfl_xor(sa4,m,64); sa5 += __shfl_xor(sa5,m,64);
    sa6 += __shfl_xor(sa6,m,64); sa7 += __shfl_xor(sa7,m,64);
    na0 += __shfl_xor(na0,m,64); na1 += __shfl_xor(na1,m,64);
    na2 += __shfl_xor(na2,m,64); na3 += __shfl_xor(na3,m,64);
    na4 += __shfl_xor(na4,m,64); na5 += __shfl_xor(na5,m,64);
    na6 += __shfl_xor(na6,m,64); na7 += __shfl_xor(na7,m,64);
    sb0 += __shfl_xor(sb0,m,64); sb1 += __shfl_xor(sb1,m,64);
    sb2 += __shfl_xor(sb2,m,64); sb3 += __shfl_xor(sb3,m,64);
    sb4 += __shfl_xor(sb4,m,64); sb5 += __shfl_xor(sb5,m,64);
    sb6 += __shfl_xor(sb6,m,64); sb7 += __shfl_xor(sb7,m,64);
    nb0 += __shfl_xor(nb0,m,64); nb1 += __shfl_xor(nb1,m,64);
    nb2 += __shfl_xor(nb2,m,64); nb3 += __shfl_xor(nb3,m,64);
    nb4 += __shfl_xor(nb4,m,64); nb5 += __shfl_xor(nb5,m,64);
    nb6 += __shfl_xor(nb6,m,64); nb7 += __shfl_xor(nb7,m,64);
  }
  if (sub == 0){
    float ig = inv_sqrt[g];
    uint4 o;
    o.x = (uint)f2b(sa0) | ((uint)f2b(sa1) << 16);
    o.y = (uint)f2b(sa2) | ((uint)f2b(sa3) << 16);
    o.z = (uint)f2b(sa4) | ((uint)f2b(sa5) << 16);
    o.w = (uint)f2b(sa6) | ((uint)f2b(sa7) << 16);
    *reinterpret_cast<uint4*>(os0 + (size_t)g*64 + cb) = o;
    o.x = (uint)f2b(na0*ig) | ((uint)f2b(na1*ig) << 16);
    o.y = (uint)f2b(na2*ig) | ((uint)f2b(na3*ig) << 16);
    o.z = (uint)f2b(na4*ig) | ((uint)f2b(na5*ig) << 16);
    o.w = (uint)f2b(na6*ig) | ((uint)f2b(na7*ig) << 16);
    *reinterpret_cast<uint4*>(on0 + (size_t)g*64 + cb) = o;
    o.x = (uint)f2b(sb0) | ((uint)f2b(sb1) << 16);
    o.y = (uint)f2b(sb2) | ((uint)f2b(sb3) << 16);
    o.z = (uint)f2b(sb4) | ((uint)f2b(sb5) << 16);
    o.w = (uint)f2b(sb6) | ((uint)f2b(sb7) << 16);
    *reinterpret_cast<uint4*>(os1 + (size_t)g*64 + cb) = o;
    o.x = (uint)f2b(nb0*ig) | ((uint)f2b(nb1*ig) << 16);
    o.y = (uint)f2b(nb2*ig) | ((uint)f2b(nb3*ig) << 16);
    o.z = (uint)f2b(nb4*ig) | ((uint)f2b(nb5*ig) << 16);
    o.w = (uint)f2b(nb6*ig) | ((uint)f2b(nb7*ig) << 16);
    *reinterpret_cast<uint4*>(on1 + (size_t)g*64 + cb) = o;
  }
}

// ---------------- fused mixed-op step ----------------
struct StepArgs {
  const u16* h[5]; const u16* asum[5]; const u16* anorm[5];
  int rs[5]; int slot[5]; int J;
  const u16* wpk; const float* inv_deg; const u16* x0;
  u16* out; int rs_out; int Nn;
};

// 8 MFMAs of one 64x64 matrix (local idx within a 32KB half) against a
// 16-row A-fragment pair
__device__ __forceinline__ void mm8(const bh8 (&af)[2], const u16* wb, int mat,
                                    int t, int q, f4 (&acc)[4]){
  #pragma unroll
  for (int kb=0;kb<2;kb++)
    #pragma unroll
    for (int nt=0;nt<4;nt++){
      bh8 bf = ld8(wb + (mat<<12) + ((nt*16+t)<<6) + ((((kb<<2)|q) ^ (t&7))<<3));
      acc[nt] = __builtin_amdgcn_mfma_f32_16x16x32_bf16(af[kb], bf, acc[nt], 0, 0, 0);
    }
}

// round-9 geometry (512 thr, 16 waves/CU via 2 blocks, 64KB LDS, reg-copy
// staging) + half-split ping-pong pipeline (round 12).
__global__ __launch_bounds__(512)
void k_step(StepArgs A){
  __shared__ __align__(16) u16 wlds[2][4*4096];   // 2 x 32 KB halves
  int tid = threadIdx.x, wv = tid>>6, lane = tid&63, q = lane>>4, t = lane&15;
  int blk = xcd_swz(blockIdx.x, gridDim.x);
  int row0 = blk*128 + wv*16;
  int rA = row0 + t;
  int q8 = q*8;
  f4 idg = *reinterpret_cast<const f4*>(A.inv_deg + row0 + q*4);
  const u16* xp = A.x0 + (size_t)rA*64;
  bh8 fx[2];
  fx[0]=ld8(xp+q8); fx[1]=ld8(xp+32+q8);

  f4 oacc[4];
  #pragma unroll
  for (int b=0;b<4;b++) oacc[b] = (f4){0.f,0.f,0.f,0.f};

  // stage one 32KB half (2048 uint4) with 512 threads: 4 chunks/thread
  auto stageH = [&](int slot, int half, int buf){
    const uint4* ws = reinterpret_cast<const uint4*>(A.wpk) + ((size_t)slot << 12) + (half<<11);
    uint4* wd = reinterpret_cast<uint4*>(&wlds[buf][0]);
    #pragma unroll
    for (int i=0;i<4;i++) wd[tid + i*512] = ws[tid + i*512];
  };

  // prologue: half0 of slot[0] -> buf0
  stageH(A.slot[0], 0, 0);
  __syncthreads();

  for (int j = 0; j < A.J; ++j){
    // ---- phase0: stage half1(j)->buf1 ; compute half0 from buf0 ----
    stageH(A.slot[j], 1, 1);

    const u16* h = A.h[j]; int rs = A.rs[j];
    const u16* hp = h + (size_t)rA*rs;
    const u16* sp = A.asum[j] + (size_t)rA*64;
    const u16* np = A.anorm[j] + (size_t)rA*64;
    bh8 fh[2], fs[2], fn[2];
    fh[0]=ld8(hp+q8); fh[1]=ld8(hp+32+q8);
    fs[0]=ld8(sp+q8); fs[1]=ld8(sp+32+q8);
    fn[0]=ld8(np+q8); fn[1]=ld8(np+32+q8);

    const u16* b0 = &wlds[0][0];
    mm8(fh, b0, 0, t, q, oacc);            // old mat1: wv3*W_self+wv5*W_gc1+wv1*I
    mm8(fs, b0, 1, t, q, oacc);            // old mat4: wv5*W_gc2 @ s_sum
    f4 p[4];
    #pragma unroll
    for (int b=0;b<4;b++) p[b] = (f4){0.f,0.f,0.f,0.f};
    mm8(fh, b0, 2, t, q, p);               // old mat5: relu(h @ wv6*W_mlp)
    #pragma unroll
    for (int nt=0;nt<4;nt++)
      #pragma unroll
      for (int r=0;r<4;r++) oacc[nt][r] += fmaxf(p[nt][r], 0.f);
    #pragma unroll
    for (int b=0;b<4;b++) p[b] = (f4){0.f,0.f,0.f,0.f};
    mm8(fh, b0, 3, t, q, p);               // old mat3: relu((h+s)@W_gin)
    mm8(fs, b0, 3, t, q, p);
    #pragma unroll
    for (int nt=0;nt<4;nt++)
      #pragma unroll
      for (int r=0;r<4;r++) oacc[nt][r] += fmaxf(p[nt][r], 0.f);

    __syncthreads();   // buf1 staged+visible; all waves done reading buf0

    // ---- phase1: stage half0(j+1)->buf0 ; compute half1 from buf1 ----
    if (j+1 < A.J) stageH(A.slot[j+1], 0, 0);

    const u16* b1 = &wlds[1][0];
    #pragma unroll
    for (int b=0;b<4;b++) p[b] = (f4){0.f,0.f,0.f,0.f};
    mm8(fn, b1, 0, t, q, p);               // old mat0: relu(s_norm @ W_gcn)
    #pragma unroll
    for (int nt=0;nt<4;nt++)
      #pragma unroll
      for (int r=0;r<4;r++) oacc[nt][r] += fmaxf(p[nt][r], 0.f);
    #pragma unroll
    for (int b=0;b<4;b++) p[b] = (f4){0.f,0.f,0.f,0.f};
    mm8(fn, b1, 1, t, q, p);               // old mat6: 0.9*wv7*W_gcnii @ sn
    mm8(fx, b1, 2, t, q, p);               // old mat7: 0.1*wv7*W_gcnii @ x0
    #pragma unroll
    for (int nt=0;nt<4;nt++)
      #pragma unroll
      for (int r=0;r<4;r++) oacc[nt][r] += fmaxf(p[nt][r], 0.f);
    #pragma unroll
    for (int b=0;b<4;b++) p[b] = (f4){0.f,0.f,0.f,0.f};
    mm8(fs, b1, 3, t, q, p);               // old mat2: inv_deg*(s_sum @ W_nei)
    #pragma unroll
    for (int nt=0;nt<4;nt++)
      #pragma unroll
      for (int r=0;r<4;r++) oacc[nt][r] += idg[r]*p[nt][r];

    if (j+1 < A.J) __syncthreads();   // buf0 staged; all waves done reading buf1
  }

  #pragma unroll
  for (int nt=0;nt<4;nt++)
    #pragma unroll
    for (int r=0;r<4;r++){
      int rr = row0 + q*4 + r;
      if (rr < A.Nn) A.out[(size_t)rr*A.rs_out + nt*16 + t] = f2b(oacc[nt][r]);
    }
}

// ---------------- classifier: MFMA GEMM [N,256]x[256,48] with bias ----------------
__global__ __launch_bounds__(256) void k_cls_mm(const u16* A, const u16* Bp,
                                                const float* bvec, float* out, int Nn){
  int tid = threadIdx.x, wv = tid>>6, lane = tid&63, q = lane>>4, t = lane&15;
  int row0 = blockIdx.x*128 + wv*32;
  f4 acc[2][3];
  #pragma unroll
  for (int a=0;a<2;a++)
    #pragma unroll
    for (int b=0;b<3;b++) acc[a][b] = (f4){0.f,0.f,0.f,0.f};
  const u16* arow0 = A + (size_t)(row0 + t)*256 + q*8;
  const u16* arow1 = arow0 + (size_t)16*256;
  const u16* brow  = Bp + (size_t)t*256 + q*8;
  #pragma unroll
  for (int kb = 0; kb < 8; ++kb){
    bh8 a0 = ld8(arow0 + kb*32);
    bh8 a1 = ld8(arow1 + kb*32);
    #pragma unroll
    for (int nt=0; nt<3; ++nt){
      bh8 bf = ld8(brow + (size_t)nt*16*256 + kb*32);
      acc[0][nt] = __builtin_amdgcn_mfma_f32_16x16x32_bf16(a0, bf, acc[0][nt], 0, 0, 0);
      acc[1][nt] = __builtin_amdgcn_mfma_f32_16x16x32_bf16(a1, bf, acc[1][nt], 0, 0, 0);
    }
  }
  #pragma unroll
  for (int rt=0;rt<2;rt++)
    #pragma unroll
    for (int nt=0;nt<3;nt++){
      int col = nt*16 + t;
      #pragma unroll
      for (int r=0;r<4;r++){
        int row = row0 + rt*16 + q*4 + r;
        if (row < Nn && col < 40) out[(size_t)row*40 + col] = acc[rt][nt][r] + bvec[col];
      }
    }
}

// ---------------- host ----------------
extern "C" void kernel_launch(void* const* d_in, const int* in_sizes, int n_in,
                              void* d_out, int out_size, void* d_ws, size_t ws_size,
                              hipStream_t stream){
  (void)n_in; (void)out_size; (void)ws_size;
  const float* x      = (const float*)d_in[0];
  const int*   ei     = (const int*)d_in[1];
  const float* alphas = (const float*)d_in[2];
  const float* stem_W = (const float*)d_in[3];
  const float* pre_W  = (const float*)d_in[4];
  const float* p00    = (const float*)d_in[5];
  const float* p10    = (const float*)d_in[6];
  const float* p01    = (const float*)d_in[7];
  const float* p11    = (const float*)d_in[8];
  const float* clsW = (const float*)d_in[17];
  const float* clsb = (const float*)d_in[18];

  int N = in_sizes[0] / 128;
  int E = in_sizes[1] / 2;
  const int* esrc = ei;
  const int* edst = ei + E;

  char* p = (char*)d_ws;
  auto carve = [&](size_t bytes) -> char* {
    char* r = p; p += (bytes + 255) & ~(size_t)255; return r;
  };
  int*   hist    = (int*)carve((size_t)NBK*4);
  int*   bbase   = (int*)carve((size_t)(NBK+1)*4);
  int*   bcursor = (int*)carve((size_t)NBK*4);
  unsigned* bkt  = (unsigned*)carve((size_t)E*4);
  int*   off     = (int*)carve((size_t)(N+1)*4);
  int2*  csr     = (int2*)carve((size_t)E*8);
  float* inv_deg = (float*)carve((size_t)N*4);
  float* invs    = (float*)carve((size_t)N*4);
  float* wmix    = (float*)carve(14*8*4);
  float* stats   = (float*)carve(512*4);
  float* Sp      = (float*)carve((size_t)512*512*4);   // per-block partial stats
  u16* xb      = (u16*)carve((size_t)N*128*2);
  u16* spk     = (u16*)carve((size_t)256*128*2);       // fused stem(192)+pre(64) weights
  u16* p00_pk  = (u16*)carve((size_t)64*192*2);
  u16* p10_pk  = (u16*)carve((size_t)64*192*2);
  u16* p01_pk  = (u16*)carve((size_t)64*192*2);
  u16* p11_pk  = (u16*)carve((size_t)64*256*2);
  u16* cls_pk  = (u16*)carve((size_t)48*256*2);
  u16* ops_pk  = (u16*)carve((size_t)28*8*4096*2);
  u16* T       = (u16*)carve((size_t)N*256*2);
  u16* stem_o  = (u16*)carve((size_t)N*192*2);
  u16* x0b     = (u16*)carve((size_t)N*64*2);
  u16* ab      = (u16*)carve((size_t)N*128*2);
  u16* oc0     = (u16*)carve((size_t)N*256*2);
  u16* oc1     = (u16*)carve((size_t)N*256*2);
  u16* agg     = (u16*)carve((size_t)5*2*N*64*2);
  carve(262144); // tail slack for unguarded OOB-row reads

  auto aggS = [&](int j){ return agg + (size_t)j*2*N*64; };
  auto aggN = [&](int j){ return agg + (size_t)j*2*N*64 + (size_t)N*64; };

  int NB = (N + 127)/128;        // real buckets
  int gg = (N + 127)/128;
  int gstep = (N + 127)/128;     // 391 blocks -> 2 per CU
  int ag = (N + 7)/8;            // 8 nodes/block (2 per wave)
  float invN = 1.0f/(float)N;

  // ---- CSR build (bucketed) ----
  hipMemsetAsync(hist, 0, (size_t)NBK*4, stream);
  k_hist<<<256,256,0,stream>>>(edst, hist, E);
  k_scanb<<<1,512,0,stream>>>(hist, bbase, bcursor);
  k_bucket<<<256,256,0,stream>>>(esrc, edst, bcursor, bkt, E, 256);
  k_degb<<<NB,128,0,stream>>>(bkt, bbase, off, inv_deg, invs, N, E);
  k_fillb<<<NB,128,0,stream>>>(bkt, bbase, off, invs, csr, N);

  k_softmax<<<1,128,0,stream>>>(alphas, wmix);
  k_f2b<<<(N*128+255)/256,256,0,stream>>>(x, xb, N*128);

  // all weight packs in ONE launch
  {
    PackAllArgs PA;
    PA.src[0]=stem_W; PA.dst[0]=spk;          PA.K[0]=128; PA.ncol[0]=192;  // stem -> spk rows 0-191
    PA.src[1]=pre_W;  PA.dst[1]=spk+192*128;  PA.K[1]=128; PA.ncol[1]=64;   // pre  -> spk rows 192-255
    PA.src[2]=p00;    PA.dst[2]=p00_pk;       PA.K[2]=192; PA.ncol[2]=64;
    PA.src[3]=p10;    PA.dst[3]=p10_pk;       PA.K[3]=192; PA.ncol[3]=64;
    PA.src[4]=p01;    PA.dst[4]=p01_pk;       PA.K[4]=192; PA.ncol[4]=64;
    PA.src[5]=p11;    PA.dst[5]=p11_pk;       PA.K[5]=256; PA.ncol[5]=64;
    PA.src[6]=clsW;   PA.dst[6]=cls_pk;
    PA.K[6]=0; PA.ncol[6]=0;
    int b = 0;
    PA.base[0]=0;
    int sizes[7] = {128*192, 128*64, 192*64, 192*64, 192*64, 256*64, 48*256};
    for (int s=0;s<7;s++){ b += sizes[s]; PA.base[s+1]=b; }
    k_packall<<<(b+255)/256,256,0,stream>>>(PA);
  }
  {
    PackArgs PA;
    for (int i = 0; i < 8; ++i) PA.W[i] = (const float*)d_in[9+i];
    PA.wmix = wmix; PA.dst = ops_pk;
    k_pack_ops8<<<(28*8*4096+255)/256,256,0,stream>>>(PA);
  }

  // mlp: GEMM (per-block partials) -> redstats -> norm. K/ncol compile-time.
  auto mlp = [&](const u16* A, int K, const u16* Bp, int ncol, u16* outb, int rs_out, int relu){
    if (K == 192)
      hipLaunchKernelGGL(HIP_KERNEL_NAME(k_gemm<4,6>), dim3(gg), dim3(256), 0, stream, A, Bp, T, N, Sp);
    else
      hipLaunchKernelGGL(HIP_KERNEL_NAME(k_gemm<4,8>), dim3(gg), dim3(256), 0, stream, A, Bp, T, N, Sp);
    k_redstats<<<(2*ncol+3)/4,256,0,stream>>>(Sp, stats, ncol, gg);
    k_norm<<<((N*(ncol>>3))+255)/256,256,0,stream>>>(T, ncol, ncol, N, stats, outb, rs_out, relu, invN);
  };

  // fused stem (192 cols, no relu) + preprocess (64 cols, relu):
  // column-split GEMM (gg,2) with NT=8, then segmented redstats + split norm
  k_gemm2<<<dim3(gg,2),256,0,stream>>>(xb, spk, T, N, Sp);
  k_redstats2<<<128,256,0,stream>>>(Sp, stats, gg);
  k_norm2<<<(N*32+255)/256,256,0,stream>>>(T, N, stats, stem_o, x0b, invN);

  u16* ocs[2] = {oc0, oc1};
  const int slotbase[4] = {0, 2, 5, 9};
  for (int ci = 0; ci < 2; ++ci){
    const u16* s1in = (ci == 0) ? stem_o : oc0;
    int Kb   = (ci == 0) ? 192 : 256;
    const u16* pa = (ci == 0) ? p00_pk : p01_pk;
    const u16* pb = (ci == 0) ? p10_pk : p11_pk;
    mlp(stem_o, 192, pa, 64, ab, 128, 1);        // a -> ab[:, 0:64]
    mlp(s1in, Kb, pb, 64, ab + 64, 128, 1);      // b -> ab[:, 64:128]

    u16* oc = ocs[ci];
    const u16* wpk_cell = ops_pk + (size_t)ci*14*8*4096;

    k_agg2v<<<ag,256,0,stream>>>(ab, off, csr, invs,
                                 aggS(0), aggN(0), aggS(1), aggN(1), N);

    const u16* st[5] = { ab, ab + 64, oc + 0, oc + 64, oc + 128 };
    const int strs[5] = {128, 128, 256, 256, 256};
    for (int step = 0; step < 4; ++step){
      StepArgs SA{};
      int J = step + 2;
      for (int j = 0; j < J; ++j){
        SA.h[j] = st[j]; SA.rs[j] = strs[j];
        SA.asum[j] = aggS(j); SA.anorm[j] = aggN(j);
        SA.slot[j] = slotbase[step] + j;
      }
      SA.J = J; SA.wpk = wpk_cell; SA.inv_deg = inv_deg; SA.x0 = x0b;
      SA.out = oc + (size_t)step*64; SA.rs_out = 256; SA.Nn = N;
      k_step<<<gstep,512,0,stream>>>(SA);
      if (step < 3)
        hipLaunchKernelGGL(HIP_KERNEL_NAME(k_aggv<8>), dim3(ag), dim3(256), 0, stream,
                           oc + (size_t)step*64, off, csr, invs, aggS(step+2), aggN(step+2), N);
    }
  }

  k_cls_mm<<<gg,256,0,stream>>>(oc1, cls_pk, clsb, (float*)d_out, N);
}

// Round 15
// 762.945 us; speedup vs baseline: 1.0225x; 1.0150x over previous
//
#include <hip/hip_runtime.h>
#include <stdint.h>

typedef unsigned short u16;
typedef __attribute__((ext_vector_type(8))) short bh8;   // 8 x bf16 (bits)
typedef __attribute__((ext_vector_type(4))) float f4;

__device__ __forceinline__ float b2f(u16 u){ union{unsigned u; float f;} x; x.u = ((unsigned)u)<<16; return x.f; }
__device__ __forceinline__ u16 f2b(float f){ union{float f; unsigned u;} x; x.f = f; return (u16)((x.u + 0x7fffu + ((x.u>>16)&1u))>>16); }
__device__ __forceinline__ bh8 ld8(const u16* p){ return *reinterpret_cast<const bh8*>(p); }

// bijective XCD-chunked block swizzle (m204 form)
__device__ __forceinline__ int xcd_swz(int bid, int nwg){
  int q = nwg >> 3, r = nwg & 7;
  int x = bid & 7, k = bid >> 3;
  return (x < r ? x*(q+1) : r*(q+1) + (x - r)*q) + k;
}

// ---------------- graph preprocessing: bucketed counting-sort CSR build ----------------
#define NBK 512   // bucket slots (real buckets = ceil(N/128) <= 391)

__global__ __launch_bounds__(256) void k_hist(const int* dst, int* hist, int E){
  __shared__ int h[NBK];
  for (int i=threadIdx.x;i<NBK;i+=256) h[i]=0;
  __syncthreads();
  int stride = 256*gridDim.x;
  for (int i = blockIdx.x*256+threadIdx.x; i<E; i+=stride)
    atomicAdd(&h[dst[i]>>7], 1);
  __syncthreads();
  for (int i=threadIdx.x;i<NBK;i+=256){
    int v=h[i]; if (v) atomicAdd(&hist[i], v);
  }
}

__global__ __launch_bounds__(512) void k_scanb(const int* hist, int* bbase, int* bcursor){
  int t = threadIdx.x, lane = t&63, wv = t>>6;
  __shared__ int ws[8];
  int v = hist[t];
  int x = v;
  #pragma unroll
  for (int o=1;o<64;o<<=1){ int u=__shfl_up(x,(unsigned)o,64); if(lane>=o) x+=u; }
  if (lane==63) ws[wv]=x;
  __syncthreads();
  if (t<8){
    int s=ws[t];
    #pragma unroll
    for (int o=1;o<8;o<<=1){ int u=__shfl_up(s,(unsigned)o,8); if (t>=o) s+=u; }
    ws[t]=s;
  }
  __syncthreads();
  int base = (wv==0)?0:ws[wv-1];
  int ex = base + x - v;
  bbase[t]=ex; bcursor[t]=ex;
  if (t==511) bbase[512]=ex+v;
}

__global__ __launch_bounds__(256) void k_bucket(const int* src, const int* dst,
                                                int* bcursor, unsigned* bkt, int E, int nblk){
  __shared__ int h[NBK], base[NBK], lc[NBK];
  int per = (E + nblk - 1)/nblk;
  int e0 = blockIdx.x*per, e1 = min(E, e0+per);
  for (int i=threadIdx.x;i<NBK;i+=256){ h[i]=0; lc[i]=0; }
  __syncthreads();
  for (int e=e0+threadIdx.x; e<e1; e+=256) atomicAdd(&h[dst[e]>>7], 1);
  __syncthreads();
  for (int i=threadIdx.x;i<NBK;i+=256){
    int c=h[i]; base[i] = c ? atomicAdd(&bcursor[i], c) : 0;
  }
  __syncthreads();
  for (int e=e0+threadIdx.x; e<e1; e+=256){
    int d = dst[e];
    int b = d>>7;
    int r = atomicAdd(&lc[b], 1);
    bkt[base[b]+r] = ((unsigned)(d&127)<<25) | (unsigned)src[e];
  }
}

__global__ __launch_bounds__(128) void k_degb(const unsigned* bkt, const int* bbase,
                                              int* off, float* inv_deg, float* invs,
                                              int N, int E){
  int b = blockIdx.x, t = threadIdx.x;
  __shared__ int cnt[128];
  __shared__ int w0tot;
  cnt[t]=0;
  __syncthreads();
  int e0=bbase[b], e1=bbase[b+1];
  for (int e=e0+t; e<e1; e+=128) atomicAdd(&cnt[bkt[e]>>25], 1);
  __syncthreads();
  int v = cnt[t];
  int lane=t&63, wv=t>>6;
  int x=v;
  #pragma unroll
  for (int o=1;o<64;o<<=1){ int u=__shfl_up(x,(unsigned)o,64); if(lane>=o) x+=u; }
  if (t==63) w0tot=x;
  __syncthreads();
  int ex = x - v + (wv ? w0tot : 0);
  int node = b*128 + t;
  if (node < N){
    off[node] = e0 + ex;
    int d = (v<1)?1:v;
    float df=(float)d;
    inv_deg[node]=1.0f/df;
    invs[node]=rsqrtf(df);
  }
  if (b==0 && t==0) off[N]=E;
}

__global__ __launch_bounds__(128) void k_fillb(const unsigned* bkt, const int* bbase,
                                               const int* off, const float* invs,
                                               int2* csr, int N){
  int b = blockIdx.x, t = threadIdx.x;
  __shared__ int cur[128];
  int node = b*128 + t;
  cur[t] = (node < N) ? off[node] : 0;
  __syncthreads();
  int e0=bbase[b], e1=bbase[b+1];
  for (int e=e0+t; e<e1; e+=128){
    unsigned v = bkt[e];
    int i = (int)(v>>25);
    int s = (int)(v & 0x1FFFFFFu);
    int pos = atomicAdd(&cur[i], 1);
    csr[pos] = make_int2(s, __float_as_int(invs[s]));
  }
}

__global__ void k_softmax(const float* alphas, float* wmix){
  int t = threadIdx.x; int r = t >> 3, o = t & 7;
  if (r < 14){
    float v = alphas[r*8+o];
    float m = v;
    #pragma unroll
    for (int d=1; d<8; d<<=1) m = fmaxf(m, __shfl_xor(m, d, 8));
    float e = expf(v - m);
    float s = e;
    #pragma unroll
    for (int d=1; d<8; d<<=1) s += __shfl_xor(s, d, 8);
    wmix[r*8+o] = e / s;
  }
}

// ---------------- conversion / packing ----------------
__global__ void k_f2b(const float* a, u16* b, int n){
  int i = blockIdx.x*256 + threadIdx.x;
  if (i < n) b[i] = f2b(a[i]);
}

// all 7 weight-pack jobs in one launch (segmented index space).
struct PackAllArgs {
  const float* src[7];
  u16* dst[7];
  int K[7], ncol[7];
  int base[8];
};
__global__ __launch_bounds__(256) void k_packall(PackAllArgs P){
  int i = blockIdx.x*256 + threadIdx.x;
  if (i >= P.base[7]) return;
  int s = 0;
  #pragma unroll
  for (int k=1;k<7;k++) if (i >= P.base[k]) s = k;
  int e = i - P.base[s];
  if (s < 6){
    int K = P.K[s], ncol = P.ncol[s];
    int k = e / ncol, n = e - k*ncol;
    P.dst[s][(size_t)n*K + k] = f2b(P.src[s][e]);
  } else {
    int n = e >> 8, k = e & 255;
    float v = 0.f;
    if (n < 40) v = P.src[6][(size_t)(1+k)*40 + n] + P.src[6][n] * (1.f/256.f);
    P.dst[6][(size_t)n*256 + k] = f2b(v);
  }
}

// op weights with softmax-mix folding. 8 matrices per slot:
// 0: wv2*W_gcn (relu, s_norm)  1: wv3*W_self+wv5*W_gc1+wv1*I (h)
// 2: wv3*W_nei (s_sum, inv_deg row-scaled out)  3: wv4*W_gin (relu, h+s)
// 4: wv5*W_gc2 (s_sum)  5: wv6*W_mlp (relu, h)
// 6: 0.9*wv7*W_gcnii (sn)  7: 0.1*wv7*W_gcnii (x0)
// dst layout [n][k] with the k_step XOR-swizzle baked in. Identity order.
struct PackArgs { const float* W[8]; const float* wmix; u16* dst; };
__global__ void k_pack_ops8(PackArgs P){
  int i = blockIdx.x*256 + threadIdx.x;
  if (i >= 28*8*4096) return;
  int slot28 = i >> 15;
  int rem = i & 32767;
  int mat = rem >> 12;
  int e = rem & 4095;
  int k = e >> 6, n = e & 63;
  const float* wm = P.wmix + (slot28 % 14)*8;
  size_t off = (size_t)slot28*4096 + e;   // source [28][64][64] row-major [k][n]
  float v = 0.f;
  switch(mat){
    case 0: v = wm[2]*P.W[0][off]; break;
    case 1: v = wm[3]*P.W[1][off] + wm[5]*P.W[4][off] + ((k==n) ? wm[1] : 0.f); break;
    case 2: v = wm[3]*P.W[2][off]; break;
    case 3: v = wm[4]*P.W[3][off]; break;
    case 4: v = wm[5]*P.W[5][off]; break;
    case 5: v = wm[6]*P.W[6][off]; break;
    case 6: v = 0.9f*wm[7]*P.W[7][off]; break;
    case 7: v = 0.1f*wm[7]*P.W[7][off]; break;
  }
  P.dst[(((size_t)slot28*8 + mat)<<12) + (n<<6) + (((k>>3) ^ (n&7))<<3) + (k&7)] = f2b(v);
}

// ---------------- MLP: GEMM + per-block partial stats (no global atomics) ----------------
template<int NT, int NKB>
__global__ __launch_bounds__(256) void k_gemm(const u16* A, const u16* Bp,
                                              u16* Tb, int Nn, float* Sp){
  const int K = NKB*32;
  const int ldT = NT*16;
  __shared__ float sred[4][NT*16][2];
  int tid = threadIdx.x, wv = tid>>6, lane = tid&63, q = lane>>4, t = lane&15;
  int row0 = blockIdx.x*128 + wv*32;
  f4 acc[2][NT];
  #pragma unroll
  for (int a=0;a<2;a++)
    #pragma unroll
    for (int b=0;b<NT;b++) acc[a][b] = (f4){0.f,0.f,0.f,0.f};
  const u16* arow0 = A + (size_t)(row0 + t)*K + q*8;
  const u16* arow1 = arow0 + (size_t)16*K;
  const u16* brow  = Bp + (size_t)t*K + q*8;
  #pragma unroll
  for (int kb = 0; kb < NKB; ++kb){
    bh8 a0 = ld8(arow0 + kb*32);
    bh8 a1 = ld8(arow1 + kb*32);
    #pragma unroll
    for (int nt=0; nt<NT; ++nt){
      bh8 bf = ld8(brow + (size_t)nt*16*K + kb*32);
      acc[0][nt] = __builtin_amdgcn_mfma_f32_16x16x32_bf16(a0, bf, acc[0][nt], 0, 0, 0);
      acc[1][nt] = __builtin_amdgcn_mfma_f32_16x16x32_bf16(a1, bf, acc[1][nt], 0, 0, 0);
    }
  }
  #pragma unroll
  for (int nt=0;nt<NT;nt++){
    float ps = 0.f, pq = 0.f;
    #pragma unroll
    for (int rt=0;rt<2;rt++)
      #pragma unroll
      for (int r=0;r<4;r++){
        int row = row0 + rt*16 + q*4 + r;
        float v = acc[rt][nt][r];
        if (row < Nn){
          Tb[(size_t)row*ldT + nt*16 + t] = f2b(v);
          ps += v; pq += v*v;
        }
      }
    ps += __shfl_xor(ps, 16, 64); pq += __shfl_xor(pq, 16, 64);
    ps += __shfl_xor(ps, 32, 64); pq += __shfl_xor(pq, 32, 64);
    if (q == 0){ sred[wv][nt*16 + t][0] = ps; sred[wv][nt*16 + t][1] = pq; }
  }
  __syncthreads();
  if (tid < NT*16){
    float s = sred[0][tid][0] + sred[1][tid][0] + sred[2][tid][0] + sred[3][tid][0];
    float qq = sred[0][tid][1] + sred[1][tid][1] + sred[2][tid][1] + sred[3][tid][1];
    float* sp = Sp + (size_t)blockIdx.x*(2*NT*16);
    sp[tid] = s;
    sp[NT*16 + tid] = qq;        // coalesced plain stores, no contention
  }
}

// fused stem+pre GEMM, column-split (round-13): grid (gg,2), NT=8 per half,
// acc 64 VGPR (no VGPR-cliff regressions), half the epilogue stores/thread.
__global__ __launch_bounds__(256) void k_gemm2(const u16* A, const u16* Bp,
                                               u16* Tb, int Nn, float* Sp){
  const int K = 128;
  __shared__ float sred[4][128][2];
  int tid = threadIdx.x, wv = tid>>6, lane = tid&63, q = lane>>4, t = lane&15;
  int row0 = blockIdx.x*128 + wv*32;
  int cb0 = blockIdx.y << 7;
  f4 acc[2][8];
  #pragma unroll
  for (int a=0;a<2;a++)
    #pragma unroll
    for (int b=0;b<8;b++) acc[a][b] = (f4){0.f,0.f,0.f,0.f};
  const u16* arow0 = A + (size_t)(row0 + t)*K + q*8;
  const u16* arow1 = arow0 + (size_t)16*K;
  const u16* brow  = Bp + (size_t)(cb0 + t)*K + q*8;
  #pragma unroll
  for (int kb = 0; kb < 4; ++kb){
    bh8 a0 = ld8(arow0 + kb*32);
    bh8 a1 = ld8(arow1 + kb*32);
    #pragma unroll
    for (int nt=0; nt<8; ++nt){
      bh8 bf = ld8(brow + (size_t)nt*16*K + kb*32);
      acc[0][nt] = __builtin_amdgcn_mfma_f32_16x16x32_bf16(a0, bf, acc[0][nt], 0, 0, 0);
      acc[1][nt] = __builtin_amdgcn_mfma_f32_16x16x32_bf16(a1, bf, acc[1][nt], 0, 0, 0);
    }
  }
  #pragma unroll
  for (int nt=0;nt<8;nt++){
    float ps = 0.f, pq = 0.f;
    #pragma unroll
    for (int rt=0;rt<2;rt++)
      #pragma unroll
      for (int r=0;r<4;r++){
        int row = row0 + rt*16 + q*4 + r;
        float v = acc[rt][nt][r];
        if (row < Nn){
          Tb[(size_t)row*256 + cb0 + nt*16 + t] = f2b(v);
          ps += v; pq += v*v;
        }
      }
    ps += __shfl_xor(ps, 16, 64); pq += __shfl_xor(pq, 16, 64);
    ps += __shfl_xor(ps, 32, 64); pq += __shfl_xor(pq, 32, 64);
    if (q == 0){ sred[wv][nt*16 + t][0] = ps; sred[wv][nt*16 + t][1] = pq; }
  }
  __syncthreads();
  if (tid < 128){
    float s = sred[0][tid][0] + sred[1][tid][0] + sred[2][tid][0] + sred[3][tid][0];
    float qq = sred[0][tid][1] + sred[1][tid][1] + sred[2][tid][1] + sred[3][tid][1];
    float* sp = Sp + ((size_t)blockIdx.x*2 + blockIdx.y)*256;
    sp[tid] = s;
    sp[128 + tid] = qq;
  }
}

// reduce per-block partials -> S[c] (sum), S[256+c] (sumsq).
__global__ __launch_bounds__(256) void k_redstats(const float* Sp, float* S, int ncol, int nb){
  int c2 = blockIdx.x*4 + (threadIdx.x>>6);
  int lane = threadIdx.x & 63;
  if (c2 >= 2*ncol) return;
  int stride = 2*ncol;
  float s = 0.f;
  for (int b = lane; b < nb; b += 64) s += Sp[(size_t)b*stride + c2];
  #pragma unroll
  for (int m=1; m<64; m<<=1) s += __shfl_xor(s, m, 64);
  if (lane == 0){
    int c = (c2 < ncol) ? c2 : (256 + (c2 - ncol));
    S[c] = s;
  }
}

// redstats for k_gemm2's (bx,by)-segmented layout; 256 cols.
__global__ __launch_bounds__(256) void k_redstats2(const float* Sp, float* S, int nb){
  int c2 = blockIdx.x*4 + (threadIdx.x>>6);
  int lane = threadIdx.x & 63;
  if (c2 >= 512) return;
  int issum = (c2 < 256);
  int c = issum ? c2 : (c2 - 256);
  int by = c >> 7, idx = c & 127;
  const float* base = Sp + (size_t)by*256 + (issum ? 0 : 128) + idx;
  float s = 0.f;
  for (int b = lane; b < nb; b += 64) s += base[(size_t)b*512];
  #pragma unroll
  for (int m=1; m<64; m<<=1) s += __shfl_xor(s, m, 64);
  if (lane == 0) S[issum ? c : 256 + c] = s;
}

__global__ void k_norm(const u16* Tb, int ldT, int ncols, int Nn, const float* S,
                       u16* out, int rs_out, int relu, float invN){
  int i = blockIdx.x*256 + threadIdx.x;
  int nv = ncols >> 3;
  if (i >= Nn*nv) return;
  int r = i / nv, c8 = (i - r*nv)*8;
  bh8 tv = ld8(Tb + (size_t)r*ldT + c8);
  bh8 ov;
  #pragma unroll
  for (int u=0; u<8; ++u){
    int c = c8 + u;
    float m = S[c]*invN;
    float var = S[256+c]*invN - m*m;
    float xv = (b2f((u16)tv[u]) - m) * rsqrtf(var + 1e-5f);
    if (relu) xv = fmaxf(xv, 0.f);
    ov[u] = (short)f2b(xv);
  }
  *reinterpret_cast<bh8*>(out + (size_t)r*rs_out + c8) = ov;
}

// split-output norm for the fused stem+pre GEMM (256 cols in T):
// cols 0-191 -> stem_o (no relu, stride 192); cols 192-255 -> x0b (relu, stride 64)
__global__ void k_norm2(const u16* Tb, int Nn, const float* S,
                        u16* o1, u16* o2, float invN){
  int i = blockIdx.x*256 + threadIdx.x;
  if (i >= Nn*32) return;
  int r = i >> 5, c8 = (i & 31) << 3;
  bh8 tv = ld8(Tb + (size_t)r*256 + c8);
  bh8 ov;
  int relu = (c8 >= 192);
  #pragma unroll
  for (int u=0; u<8; ++u){
    int c = c8 + u;
    float m = S[c]*invN;
    float var = S[256+c]*invN - m*m;
    float xv = (b2f((u16)tv[u]) - m) * rsqrtf(var + 1e-5f);
    if (relu) xv = fmaxf(xv, 0.f);
    ov[u] = (short)f2b(xv);
  }
  if (c8 < 192)
    *reinterpret_cast<bh8*>(o1 + (size_t)r*192 + c8) = ov;
  else
    *reinterpret_cast<bh8*>(o2 + (size_t)r*64 + (c8 - 192)) = ov;
}

// ---------------- aggregation: 16B/lane gathers, 2 nodes/wave, 32 edges in flight ----------------
#define ACC8(vv, ww) { \
    float c0=__uint_as_float((vv).x<<16), c1=__uint_as_float((vv).x&0xffff0000u); \
    float c2=__uint_as_float((vv).y<<16), c3=__uint_as_float((vv).y&0xffff0000u); \
    float c4=__uint_as_float((vv).z<<16), c5=__uint_as_float((vv).z&0xffff0000u); \
    float c6=__uint_as_float((vv).w<<16), c7=__uint_as_float((vv).w&0xffff0000u); \
    s0+=c0; s1+=c1; s2+=c2; s3+=c3; s4+=c4; s5+=c5; s6+=c6; s7+=c7; \
    n0+=c0*(ww); n1+=c1*(ww); n2+=c2*(ww); n3+=c3*(ww); \
    n4+=c4*(ww); n5+=c5*(ww); n6+=c6*(ww); n7+=c7*(ww); }

template<int SHIFT>
__global__ __launch_bounds__(256) void k_aggv(const u16* h, const int* off, const int2* csr,
                                              const float* inv_sqrt, u16* out_sum, u16* out_norm, int Nn){
  int blk = xcd_swz(blockIdx.x, gridDim.x);
  int g = blk*8 + (threadIdx.x >> 5);
  if (g >= Nn) return;
  int l32 = threadIdx.x & 31;
  int sub = l32 >> 3;            // 0..3
  int cb = (l32 & 7) << 3;       // 8 channels (16B) per lane
  const u16* hp = h + cb;
  float s0=0,s1=0,s2=0,s3=0,s4=0,s5=0,s6=0,s7=0;
  float n0=0,n1=0,n2=0,n3=0,n4=0,n5=0,n6=0,n7=0;
  int e0 = off[g], e1 = off[g+1];
  int e = e0 + sub;
  for (; e + 12 < e1; e += 16){
    int2 cA = csr[e];
    int2 cB = csr[e+4];
    int2 cC = csr[e+8];
    int2 cD = csr[e+12];
    uint4 vA = *reinterpret_cast<const uint4*>(hp + (((unsigned)cA.x) << SHIFT));
    uint4 vB = *reinterpret_cast<const uint4*>(hp + (((unsigned)cB.x) << SHIFT));
    uint4 vC = *reinterpret_cast<const uint4*>(hp + (((unsigned)cC.x) << SHIFT));
    uint4 vD = *reinterpret_cast<const uint4*>(hp + (((unsigned)cD.x) << SHIFT));
    float wA = __int_as_float(cA.y), wB = __int_as_float(cB.y);
    float wC = __int_as_float(cC.y), wD = __int_as_float(cD.y);
    ACC8(vA, wA)
    ACC8(vB, wB)
    ACC8(vC, wC)
    ACC8(vD, wD)
  }
  for (; e < e1; e += 4){
    int2 cA = csr[e];
    uint4 vA = *reinterpret_cast<const uint4*>(hp + (((unsigned)cA.x) << SHIFT));
    float wA = __int_as_float(cA.y);
    ACC8(vA, wA)
  }
  #pragma unroll
  for (int m = 8; m <= 16; m <<= 1){
    s0 += __shfl_xor(s0,m,64); s1 += __shfl_xor(s1,m,64);
    s2 += __shfl_xor(s2,m,64); s3 += __shfl_xor(s3,m,64);
    s4 += __shfl_xor(s4,m,64); s5 += __shfl_xor(s5,m,64);
    s6 += __shfl_xor(s6,m,64); s7 += __shfl_xor(s7,m,64);
    n0 += __shfl_xor(n0,m,64); n1 += __shfl_xor(n1,m,64);
    n2 += __shfl_xor(n2,m,64); n3 += __shfl_xor(n3,m,64);
    n4 += __shfl_xor(n4,m,64); n5 += __shfl_xor(n5,m,64);
    n6 += __shfl_xor(n6,m,64); n7 += __shfl_xor(n7,m,64);
  }
  if (sub == 0){
    float ig = inv_sqrt[g];
    uint4 o;
    o.x = (uint)f2b(s0) | ((uint)f2b(s1) << 16);
    o.y = (uint)f2b(s2) | ((uint)f2b(s3) << 16);
    o.z = (uint)f2b(s4) | ((uint)f2b(s5) << 16);
    o.w = (uint)f2b(s6) | ((uint)f2b(s7) << 16);
    *reinterpret_cast<uint4*>(out_sum + (size_t)g*64 + cb) = o;
    o.x = (uint)f2b(n0*ig) | ((uint)f2b(n1*ig) << 16);
    o.y = (uint)f2b(n2*ig) | ((uint)f2b(n3*ig) << 16);
    o.z = (uint)f2b(n4*ig) | ((uint)f2b(n5*ig) << 16);
    o.w = (uint)f2b(n6*ig) | ((uint)f2b(n7*ig) << 16);
    *reinterpret_cast<uint4*>(out_norm + (size_t)g*64 + cb) = o;
  }
}

#define ACC8AB(va, vb, ww) { \
    float a0=__uint_as_float((va).x<<16), a1=__uint_as_float((va).x&0xffff0000u); \
    float a2=__uint_as_float((va).y<<16), a3=__uint_as_float((va).y&0xffff0000u); \
    float a4=__uint_as_float((va).z<<16), a5=__uint_as_float((va).z&0xffff0000u); \
    float a6=__uint_as_float((va).w<<16), a7=__uint_as_float((va).w&0xffff0000u); \
    float b0=__uint_as_float((vb).x<<16), b1=__uint_as_float((vb).x&0xffff0000u); \
    float b2=__uint_as_float((vb).y<<16), b3=__uint_as_float((vb).y&0xffff0000u); \
    float b4=__uint_as_float((vb).z<<16), b5=__uint_as_float((vb).z&0xffff0000u); \
    float b6=__uint_as_float((vb).w<<16), b7=__uint_as_float((vb).w&0xffff0000u); \
    sa0+=a0; sa1+=a1; sa2+=a2; sa3+=a3; sa4+=a4; sa5+=a5; sa6+=a6; sa7+=a7; \
    na0+=a0*(ww); na1+=a1*(ww); na2+=a2*(ww); na3+=a3*(ww); \
    na4+=a4*(ww); na5+=a5*(ww); na6+=a6*(ww); na7+=a7*(ww); \
    sb0+=b0; sb1+=b1; sb2+=b2; sb3+=b3; sb4+=b4; sb5+=b5; sb6+=b6; sb7+=b7; \
    nb0+=b0*(ww); nb1+=b1*(ww); nb2+=b2*(ww); nb3+=b3*(ww); \
    nb4+=b4*(ww); nb5+=b5*(ww); nb6+=b6*(ww); nb7+=b7*(ww); }

// dual-state over interleaved ab [N][128] (a at +0, b at +64); 2 nodes/wave
__global__ __launch_bounds__(256) void k_agg2v(const u16* ab, const int* off, const int2* csr,
                                               const float* inv_sqrt,
                                               u16* os0, u16* on0, u16* os1, u16* on1, int Nn){
  int blk = xcd_swz(blockIdx.x, gridDim.x);
  int g = blk*8 + (threadIdx.x >> 5);
  if (g >= Nn) return;
  int l32 = threadIdx.x & 31;
  int sub = l32 >> 3;
  int cb = (l32 & 7) << 3;
  const u16* hp = ab + cb;
  float sa0=0,sa1=0,sa2=0,sa3=0,sa4=0,sa5=0,sa6=0,sa7=0;
  float na0=0,na1=0,na2=0,na3=0,na4=0,na5=0,na6=0,na7=0;
  float sb0=0,sb1=0,sb2=0,sb3=0,sb4=0,sb5=0,sb6=0,sb7=0;
  float nb0=0,nb1=0,nb2=0,nb3=0,nb4=0,nb5=0,nb6=0,nb7=0;
  int e0 = off[g], e1 = off[g+1];
  int e = e0 + sub;
  for (; e + 4 < e1; e += 8){
    int2 cA = csr[e];
    int2 cB = csr[e+4];
    const u16* rpA = hp + (((unsigned)cA.x) << 7);
    const u16* rpB = hp + (((unsigned)cB.x) << 7);
    uint4 vaA = *reinterpret_cast<const uint4*>(rpA);
    uint4 vbA = *reinterpret_cast<const uint4*>(rpA + 64);
    uint4 vaB = *reinterpret_cast<const uint4*>(rpB);
    uint4 vbB = *reinterpret_cast<const uint4*>(rpB + 64);
    float wA = __int_as_float(cA.y), wB = __int_as_float(cB.y);
    ACC8AB(vaA, vbA, wA)
    ACC8AB(vaB, vbB, wB)
  }
  if (e < e1){
    int2 cA = csr[e];
    const u16* rpA = hp + (((unsigned)cA.x) << 7);
    uint4 vaA = *reinterpret_cast<const uint4*>(rpA);
    uint4 vbA = *reinterpret_cast<const uint4*>(rpA + 64);
    float wA = __int_as_float(cA.y);
    ACC8AB(vaA, vbA, wA)
  }
  #pragma unroll
  for (int m = 8; m <= 16; m <<= 1){
    sa0 += __shfl_xor(sa0,m,64); sa1 += __shfl_xor(sa1,m,64);
    sa2 += __shfl_xor(sa2,m,64); sa3 += __shfl_xor(sa3,m,64);
    sa4 += __shfl_xor(sa4,m,64); sa5 += __shfl_xor(sa5,m,64);
    sa6 += __shfl_xor(sa6,m,64); sa7 += __shfl_xor(sa7,m,64);
    na0 += __shfl_xor(na0,m,64); na1 += __shfl_xor(na1,m,64);
    na2 += __shfl_xor(na2,m,64); na3 += __shfl_xor(na3,m,64);
    na4 += __shfl_xor(na4,m,64); na5 += __shfl_xor(na5,m,64);
    na6 += __shfl_xor(na6,m,64); na7 += __shfl_xor(na7,m,64);
    sb0 += __shfl_xor(sb0,m,64); sb1 += __shfl_xor(sb1,m,64);
    sb2 += __shfl_xor(sb2,m,64); sb3 += __shfl_xor(sb3,m,64);
    sb4 += __shfl_xor(sb4,m,64); sb5 += __shfl_xor(sb5,m,64);
    sb6 += __shfl_xor(sb6,m,64); sb7 += __shfl_xor(sb7,m,64);
    nb0 += __shfl_xor(nb0,m,64); nb1 += __shfl_xor(nb1,m,64);
    nb2 += __shfl_xor(nb2,m,64); nb3 += __shfl_xor(nb3,m,64);
    nb4 += __shfl_xor(nb4,m,64); nb5 += __shfl_xor(nb5,m,64);
    nb6 += __shfl_xor(nb6,m,64); nb7 += __shfl_xor(nb7,m,64);
  }
  if (sub == 0){
    float ig = inv_sqrt[g];
    uint4 o;
    o.x = (uint)f2b(sa0) | ((uint)f2b(sa1) << 16);
    o.y = (uint)f2b(sa2) | ((uint)f2b(sa3) << 16);
    o.z = (uint)f2b(sa4) | ((uint)f2b(sa5) << 16);
    o.w = (uint)f2b(sa6) | ((uint)f2b(sa7) << 16);
    *reinterpret_cast<uint4*>(os0 + (size_t)g*64 + cb) = o;
    o.x = (uint)f2b(na0*ig) | ((uint)f2b(na1*ig) << 16);
    o.y = (uint)f2b(na2*ig) | ((uint)f2b(na3*ig) << 16);
    o.z = (uint)f2b(na4*ig) | ((uint)f2b(na5*ig) << 16);
    o.w = (uint)f2b(na6*ig) | ((uint)f2b(na7*ig) << 16);
    *reinterpret_cast<uint4*>(on0 + (size_t)g*64 + cb) = o;
    o.x = (uint)f2b(sb0) | ((uint)f2b(sb1) << 16);
    o.y = (uint)f2b(sb2) | ((uint)f2b(sb3) << 16);
    o.z = (uint)f2b(sb4) | ((uint)f2b(sb5) << 16);
    o.w = (uint)f2b(sb6) | ((uint)f2b(sb7) << 16);
    *reinterpret_cast<uint4*>(os1 + (size_t)g*64 + cb) = o;
    o.x = (uint)f2b(nb0*ig) | ((uint)f2b(nb1*ig) << 16);
    o.y = (uint)f2b(nb2*ig) | ((uint)f2b(nb3*ig) << 16);
    o.z = (uint)f2b(nb4*ig) | ((uint)f2b(nb5*ig) << 16);
    o.w = (uint)f2b(nb6*ig) | ((uint)f2b(nb7*ig) << 16);
    *reinterpret_cast<uint4*>(on1 + (size_t)g*64 + cb) = o;
  }
}

// ---------------- fused mixed-op step ----------------
struct StepArgs {
  const u16* h[5]; const u16* asum[5]; const u16* anorm[5];
  int rs[5]; int slot[5]; int J;
  const u16* wpk; const float* inv_deg; const u16* x0;
  u16* out; int rs_out; int Nn;
};

// 8 MFMAs of one 64x64 matrix against a 16-row A-fragment pair
__device__ __forceinline__ void mm8(const bh8 (&af)[2], const u16* wlds, int mat,
                                    int t, int q, f4 (&acc)[4]){
  #pragma unroll
  for (int kb=0;kb<2;kb++)
    #pragma unroll
    for (int nt=0;nt<4;nt++){
      bh8 bf = ld8(wlds + (mat<<12) + ((nt*16+t)<<6) + ((((kb<<2)|q) ^ (t&7))<<3));
      acc[nt] = __builtin_amdgcn_mfma_f32_16x16x32_bf16(af[kb], bf, acc[nt], 0, 0, 0);
    }
}

// k_step = round-11's single-buffer variant (measured optimum 44.0us):
// 512 threads, 8 waves x 16 rows = 128 rows/block, grid 391, 64KB LDS =>
// 2 blocks/CU, 16 waves/CU, uint4 reg-copy staging, XCD swizzle.
__global__ __launch_bounds__(512)
void k_step(StepArgs A){
  __shared__ __align__(16) u16 wlds[8*4096];   // 64 KB, swizzle baked into ops_pk
  int tid = threadIdx.x, wv = tid>>6, lane = tid&63, q = lane>>4, t = lane&15;
  int blk = xcd_swz(blockIdx.x, gridDim.x);
  int row0 = blk*128 + wv*16;
  int rA = row0 + t;
  int q8 = q*8;
  f4 idg = *reinterpret_cast<const f4*>(A.inv_deg + row0 + q*4);
  const u16* xp = A.x0 + (size_t)rA*64;
  bh8 fx[2];
  fx[0]=ld8(xp+q8); fx[1]=ld8(xp+32+q8);

  f4 oacc[4];
  #pragma unroll
  for (int b=0;b<4;b++) oacc[b] = (f4){0.f,0.f,0.f,0.f};

  uint4* wdst = reinterpret_cast<uint4*>(wlds);
  for (int j = 0; j < A.J; ++j){
    if (j) __syncthreads();        // all waves done reading wlds[j-1]
    const uint4* wsrc = reinterpret_cast<const uint4*>(A.wpk) + ((size_t)A.slot[j] << 12);
    #pragma unroll
    for (int i = 0; i < 8; ++i) wdst[tid + i*512] = wsrc[tid + i*512];

    // A-fragment loads issued while staging flies
    const u16* h = A.h[j]; int rs = A.rs[j];
    const u16* hp = h + (size_t)rA*rs;
    const u16* sp = A.asum[j] + (size_t)rA*64;
    const u16* np = A.anorm[j] + (size_t)rA*64;
    bh8 fh[2], fs[2], fn[2];
    fh[0]=ld8(hp+q8); fh[1]=ld8(hp+32+q8);
    fs[0]=ld8(sp+q8); fs[1]=ld8(sp+32+q8);
    fn[0]=ld8(np+q8); fn[1]=ld8(np+32+q8);

    __syncthreads();               // staged weights visible

    mm8(fh, wlds, 1, t, q, oacc);          // wv3*W_self + wv5*W_gc1 + wv1*I
    mm8(fs, wlds, 4, t, q, oacc);          // wv5*W_gc2 @ s_sum
    f4 p[4];
    #pragma unroll
    for (int b=0;b<4;b++) p[b] = (f4){0.f,0.f,0.f,0.f};
    mm8(fh, wlds, 5, t, q, p);             // relu(h @ wv6*W_mlp)
    #pragma unroll
    for (int nt=0;nt<4;nt++)
      #pragma unroll
      for (int r=0;r<4;r++) oacc[nt][r] += fmaxf(p[nt][r], 0.f);
    #pragma unroll
    for (int b=0;b<4;b++) p[b] = (f4){0.f,0.f,0.f,0.f};
    mm8(fh, wlds, 3, t, q, p);             // relu((h+s)@W_gin)
    mm8(fs, wlds, 3, t, q, p);
    #pragma unroll
    for (int nt=0;nt<4;nt++)
      #pragma unroll
      for (int r=0;r<4;r++) oacc[nt][r] += fmaxf(p[nt][r], 0.f);
    #pragma unroll
    for (int b=0;b<4;b++) p[b] = (f4){0.f,0.f,0.f,0.f};
    mm8(fn, wlds, 0, t, q, p);             // relu(s_norm @ W_gcn)
    #pragma unroll
    for (int nt=0;nt<4;nt++)
      #pragma unroll
      for (int r=0;r<4;r++) oacc[nt][r] += fmaxf(p[nt][r], 0.f);
    #pragma unroll
    for (int b=0;b<4;b++) p[b] = (f4){0.f,0.f,0.f,0.f};
    mm8(fn, wlds, 6, t, q, p);             // relu(0.9 sn @ W + 0.1 x0 @ W)
    mm8(fx, wlds, 7, t, q, p);
    #pragma unroll
    for (int nt=0;nt<4;nt++)
      #pragma unroll
      for (int r=0;r<4;r++) oacc[nt][r] += fmaxf(p[nt][r], 0.f);
    #pragma unroll
    for (int b=0;b<4;b++) p[b] = (f4){0.f,0.f,0.f,0.f};
    mm8(fs, wlds, 2, t, q, p);             // inv_deg * (s_sum @ W_nei)
    #pragma unroll
    for (int nt=0;nt<4;nt++)
      #pragma unroll
      for (int r=0;r<4;r++) oacc[nt][r] += idg[r]*p[nt][r];
  }

  #pragma unroll
  for (int nt=0;nt<4;nt++)
    #pragma unroll
    for (int r=0;r<4;r++){
      int rr = row0 + q*4 + r;
      if (rr < A.Nn) A.out[(size_t)rr*A.rs_out + nt*16 + t] = f2b(oacc[nt][r]);
    }
}

// ---------------- classifier: MFMA GEMM [N,256]x[256,48] with bias ----------------
__global__ __launch_bounds__(256) void k_cls_mm(const u16* A, const u16* Bp,
                                                const float* bvec, float* out, int Nn){
  int tid = threadIdx.x, wv = tid>>6, lane = tid&63, q = lane>>4, t = lane&15;
  int row0 = blockIdx.x*128 + wv*32;
  f4 acc[2][3];
  #pragma unroll
  for (int a=0;a<2;a++)
    #pragma unroll
    for (int b=0;b<3;b++) acc[a][b] = (f4){0.f,0.f,0.f,0.f};
  const u16* arow0 = A + (size_t)(row0 + t)*256 + q*8;
  const u16* arow1 = arow0 + (size_t)16*256;
  const u16* brow  = Bp + (size_t)t*256 + q*8;
  #pragma unroll
  for (int kb = 0; kb < 8; ++kb){
    bh8 a0 = ld8(arow0 + kb*32);
    bh8 a1 = ld8(arow1 + kb*32);
    #pragma unroll
    for (int nt=0; nt<3; ++nt){
      bh8 bf = ld8(brow + (size_t)nt*16*256 + kb*32);
      acc[0][nt] = __builtin_amdgcn_mfma_f32_16x16x32_bf16(a0, bf, acc[0][nt], 0, 0, 0);
      acc[1][nt] = __builtin_amdgcn_mfma_f32_16x16x32_bf16(a1, bf, acc[1][nt], 0, 0, 0);
    }
  }
  #pragma unroll
  for (int rt=0;rt<2;rt++)
    #pragma unroll
    for (int nt=0;nt<3;nt++){
      int col = nt*16 + t;
      #pragma unroll
      for (int r=0;r<4;r++){
        int row = row0 + rt*16 + q*4 + r;
        if (row < Nn && col < 40) out[(size_t)row*40 + col] = acc[rt][nt][r] + bvec[col];
      }
    }
}

// ---------------- host ----------------
extern "C" void kernel_launch(void* const* d_in, const int* in_sizes, int n_in,
                              void* d_out, int out_size, void* d_ws, size_t ws_size,
                              hipStream_t stream){
  (void)n_in; (void)out_size; (void)ws_size;
  const float* x      = (const float*)d_in[0];
  const int*   ei     = (const int*)d_in[1];
  const float* alphas = (const float*)d_in[2];
  const float* stem_W = (const float*)d_in[3];
  const float* pre_W  = (const float*)d_in[4];
  const float* p00    = (const float*)d_in[5];
  const float* p10    = (const float*)d_in[6];
  const float* p01    = (const float*)d_in[7];
  const float* p11    = (const float*)d_in[8];
  const float* clsW = (const float*)d_in[17];
  const float* clsb = (const float*)d_in[18];

  int N = in_sizes[0] / 128;
  int E = in_sizes[1] / 2;
  const int* esrc = ei;
  const int* edst = ei + E;

  char* p = (char*)d_ws;
  auto carve = [&](size_t bytes) -> char* {
    char* r = p; p += (bytes + 255) & ~(size_t)255; return r;
  };
  int*   hist    = (int*)carve((size_t)NBK*4);
  int*   bbase   = (int*)carve((size_t)(NBK+1)*4);
  int*   bcursor = (int*)carve((size_t)NBK*4);
  unsigned* bkt  = (unsigned*)carve((size_t)E*4);
  int*   off     = (int*)carve((size_t)(N+1)*4);
  int2*  csr     = (int2*)carve((size_t)E*8);
  float* inv_deg = (float*)carve((size_t)N*4);
  float* invs    = (float*)carve((size_t)N*4);
  float* wmix    = (float*)carve(14*8*4);
  float* stats   = (float*)carve(512*4);
  float* Sp      = (float*)carve((size_t)512*512*4);   // per-block partial stats
  u16* xb      = (u16*)carve((size_t)N*128*2);
  u16* spk     = (u16*)carve((size_t)256*128*2);       // fused stem(192)+pre(64) weights
  u16* p00_pk  = (u16*)carve((size_t)64*192*2);
  u16* p10_pk  = (u16*)carve((size_t)64*192*2);
  u16* p01_pk  = (u16*)carve((size_t)64*192*2);
  u16* p11_pk  = (u16*)carve((size_t)64*256*2);
  u16* cls_pk  = (u16*)carve((size_t)48*256*2);
  u16* ops_pk  = (u16*)carve((size_t)28*8*4096*2);
  u16* T       = (u16*)carve((size_t)N*256*2);
  u16* stem_o  = (u16*)carve((size_t)N*192*2);
  u16* x0b     = (u16*)carve((size_t)N*64*2);
  u16* ab      = (u16*)carve((size_t)N*128*2);
  u16* oc0     = (u16*)carve((size_t)N*256*2);
  u16* oc1     = (u16*)carve((size_t)N*256*2);
  u16* agg     = (u16*)carve((size_t)5*2*N*64*2);
  carve(262144); // tail slack for unguarded OOB-row reads

  auto aggS = [&](int j){ return agg + (size_t)j*2*N*64; };
  auto aggN = [&](int j){ return agg + (size_t)j*2*N*64 + (size_t)N*64; };

  int NB = (N + 127)/128;        // real buckets
  int gg = (N + 127)/128;
  int gstep = (N + 127)/128;     // 391 blocks -> 2 per CU
  int ag = (N + 7)/8;            // 8 nodes/block (2 per wave)
  float invN = 1.0f/(float)N;

  // ---- CSR build (bucketed) ----
  hipMemsetAsync(hist, 0, (size_t)NBK*4, stream);
  k_hist<<<256,256,0,stream>>>(edst, hist, E);
  k_scanb<<<1,512,0,stream>>>(hist, bbase, bcursor);
  k_bucket<<<256,256,0,stream>>>(esrc, edst, bcursor, bkt, E, 256);
  k_degb<<<NB,128,0,stream>>>(bkt, bbase, off, inv_deg, invs, N, E);
  k_fillb<<<NB,128,0,stream>>>(bkt, bbase, off, invs, csr, N);

  k_softmax<<<1,128,0,stream>>>(alphas, wmix);
  k_f2b<<<(N*128+255)/256,256,0,stream>>>(x, xb, N*128);

  // all weight packs in ONE launch
  {
    PackAllArgs PA;
    PA.src[0]=stem_W; PA.dst[0]=spk;          PA.K[0]=128; PA.ncol[0]=192;  // stem -> spk rows 0-191
    PA.src[1]=pre_W;  PA.dst[1]=spk+192*128;  PA.K[1]=128; PA.ncol[1]=64;   // pre  -> spk rows 192-255
    PA.src[2]=p00;    PA.dst[2]=p00_pk;       PA.K[2]=192; PA.ncol[2]=64;
    PA.src[3]=p10;    PA.dst[3]=p10_pk;       PA.K[3]=192; PA.ncol[3]=64;
    PA.src[4]=p01;    PA.dst[4]=p01_pk;       PA.K[4]=192; PA.ncol[4]=64;
    PA.src[5]=p11;    PA.dst[5]=p11_pk;       PA.K[5]=256; PA.ncol[5]=64;
    PA.src[6]=clsW;   PA.dst[6]=cls_pk;
    PA.K[6]=0; PA.ncol[6]=0;
    int b = 0;
    PA.base[0]=0;
    int sizes[7] = {128*192, 128*64, 192*64, 192*64, 192*64, 256*64, 48*256};
    for (int s=0;s<7;s++){ b += sizes[s]; PA.base[s+1]=b; }
    k_packall<<<(b+255)/256,256,0,stream>>>(PA);
  }
  {
    PackArgs PA;
    for (int i = 0; i < 8; ++i) PA.W[i] = (const float*)d_in[9+i];
    PA.wmix = wmix; PA.dst = ops_pk;
    k_pack_ops8<<<(28*8*4096+255)/256,256,0,stream>>>(PA);
  }

  // mlp: GEMM (per-block partials) -> redstats -> norm. K/ncol compile-time.
  auto mlp = [&](const u16* A, int K, const u16* Bp, int ncol, u16* outb, int rs_out, int relu){
    if (K == 192)
      hipLaunchKernelGGL(HIP_KERNEL_NAME(k_gemm<4,6>), dim3(gg), dim3(256), 0, stream, A, Bp, T, N, Sp);
    else
      hipLaunchKernelGGL(HIP_KERNEL_NAME(k_gemm<4,8>), dim3(gg), dim3(256), 0, stream, A, Bp, T, N, Sp);
    k_redstats<<<(2*ncol+3)/4,256,0,stream>>>(Sp, stats, ncol, gg);
    k_norm<<<((N*(ncol>>3))+255)/256,256,0,stream>>>(T, ncol, ncol, N, stats, outb, rs_out, relu, invN);
  };

  // fused stem (192 cols, no relu) + preprocess (64 cols, relu):
  // column-split GEMM (gg,2) with NT=8, then segmented redstats + split norm
  k_gemm2<<<dim3(gg,2),256,0,stream>>>(xb, spk, T, N, Sp);
  k_redstats2<<<128,256,0,stream>>>(Sp, stats, gg);
  k_norm2<<<(N*32+255)/256,256,0,stream>>>(T, N, stats, stem_o, x0b, invN);

  u16* ocs[2] = {oc0, oc1};
  const int slotbase[4] = {0, 2, 5, 9};
  for (int ci = 0; ci < 2; ++ci){
    const u16* s1in = (ci == 0) ? stem_o : oc0;
    int Kb   = (ci == 0) ? 192 : 256;
    const u16* pa = (ci == 0) ? p00_pk : p01_pk;
    const u16* pb = (ci == 0) ? p10_pk : p11_pk;
    mlp(stem_o, 192, pa, 64, ab, 128, 1);        // a -> ab[:, 0:64]
    mlp(s1in, Kb, pb, 64, ab + 64, 128, 1);      // b -> ab[:, 64:128]

    u16* oc = ocs[ci];
    const u16* wpk_cell = ops_pk + (size_t)ci*14*8*4096;

    k_agg2v<<<ag,256,0,stream>>>(ab, off, csr, invs,
                                 aggS(0), aggN(0), aggS(1), aggN(1), N);

    const u16* st[5] = { ab, ab + 64, oc + 0, oc + 64, oc + 128 };
    const int strs[5] = {128, 128, 256, 256, 256};
    for (int step = 0; step < 4; ++step){
      StepArgs SA{};
      int J = step + 2;
      for (int j = 0; j < J; ++j){
        SA.h[j] = st[j]; SA.rs[j] = strs[j];
        SA.asum[j] = aggS(j); SA.anorm[j] = aggN(j);
        SA.slot[j] = slotbase[step] + j;
      }
      SA.J = J; SA.wpk = wpk_cell; SA.inv_deg = inv_deg; SA.x0 = x0b;
      SA.out = oc + (size_t)step*64; SA.rs_out = 256; SA.Nn = N;
      k_step<<<gstep,512,0,stream>>>(SA);
      if (step < 3)
        hipLaunchKernelGGL(HIP_KERNEL_NAME(k_aggv<8>), dim3(ag), dim3(256), 0, stream,
                           oc + (size_t)step*64, off, csr, invs, aggS(step+2), aggN(step+2), N);
    }
  }

  k_cls_mm<<<gg,256,0,stream>>>(oc1, cls_pk, clsb, (float*)d_out, N);
}